// Round 13
// baseline (251.247 us; speedup 1.0000x reference)
//
#include <hip/hip_runtime.h>
#include <cstdint>
#include <cstddef>

#define N_NODES  50000
#define N_EDGES  800000
#define DIM      128
#define N_GRAPHS 64
#define NB       98        // coarse buckets of 512 nodes
#define BSH      9
#define EPB      2048      // edges per k_bucket block
#define BPAD     16        // bcur padding: one counter per 64B line

typedef __attribute__((ext_vector_type(8))) short     bf16x8;
typedef __attribute__((ext_vector_type(4))) float     f32x4;

__device__ __forceinline__ int clamp_node(int v) {
    return v < 0 ? 0 : (v >= N_NODES ? N_NODES - 1 : v);
}
__device__ __forceinline__ unsigned short f2bf(float f) {
    union { float f; unsigned u; } v; v.f = f;
    unsigned r = v.u + 0x7FFF + ((v.u >> 16) & 1);   // round-to-nearest-even
    return (unsigned short)(r >> 16);
}
__device__ __forceinline__ float bflo(unsigned u) {
    union { unsigned u; float f; } v; v.u = u << 16; return v.f;
}
__device__ __forceinline__ float bfhi(unsigned u) {
    union { unsigned u; float f; } v; v.u = u & 0xFFFF0000u; return v.f;
}

// ---------------------------------------------------------------------------
// CSR build: histogram of dst, scan. edge_index arrives as int32.
// ---------------------------------------------------------------------------
__global__ void k_hist(const int* __restrict__ ei, int* __restrict__ hist) {
    int e = blockIdx.x * 256 + threadIdx.x;
    if (e < N_EDGES) atomicAdd(&hist[clamp_node(ei[N_EDGES + e])], 1);
}

__global__ void k_blocksum(const int* __restrict__ hist, int* __restrict__ bsum) {
    __shared__ int s[256];
    int base = blockIdx.x * 512;
    int t = threadIdx.x;
    int v = 0;
    if (base + t < N_NODES)       v += hist[base + t];
    if (base + 256 + t < N_NODES) v += hist[base + 256 + t];
    s[t] = v;
    __syncthreads();
    for (int off = 128; off > 0; off >>= 1) {
        if (t < off) s[t] += s[t + off];
        __syncthreads();
    }
    if (t == 0) bsum[blockIdx.x] = s[0];
}

// scan of block sums; also seeds bcur: bucket b's start = rs[b*512] = boff[b].
__global__ void k_scan_bsum(int* bsum, int nb, int* __restrict__ bcur) {
    if (threadIdx.x == 0 && blockIdx.x == 0) {
        int acc = 0;
        for (int i = 0; i < nb; ++i) {
            int v = bsum[i];
            bsum[i] = acc;
            if (i < NB) bcur[i * BPAD] = acc;
            acc += v;
        }
    }
}

// rs[n] = exclusive row start (PRISTINE, never mutated); rs[N]=E. ncur = copy.
__global__ void k_scan_write(const int* __restrict__ hist, const int* __restrict__ boff,
                             int* __restrict__ rs, int* __restrict__ ncur) {
    __shared__ int s[512];
    int t = threadIdx.x;
    int i = blockIdx.x * 512 + t;
    int v = (i < N_NODES) ? hist[i] : 0;
    s[t] = v;
    __syncthreads();
    for (int off = 1; off < 512; off <<= 1) {
        int y = (t >= off) ? s[t - off] : 0;
        __syncthreads();
        s[t] += y;
        __syncthreads();
    }
    int base = boff[blockIdx.x];
    if (i < N_NODES) {
        int st = base + s[t] - v;
        rs[i] = st; ncur[i] = st;
    }
    if (i == N_NODES - 1) rs[N_NODES] = base + s[t];
}

// ---------------------------------------------------------------------------
// Placement phase A: 391 blocks x 2048 edges; LDS counting sort into 98
// coarse buckets; bulk-append runs to global bucket regions. bcur line-padded
// + blockIdx-staggered flush (round-7 lesson: same-line cursor convoy).
// Packed entry: src (16b) | dst_local (9b) << 16.
// ---------------------------------------------------------------------------
__global__ __launch_bounds__(512) void k_bucket(const int* __restrict__ ei,
                                                int* __restrict__ bcur,
                                                unsigned* __restrict__ tmp) {
    __shared__ int cnt[128], cur[128], ofs[128];
    __shared__ int s[512];
    __shared__ unsigned list[EPB];
    int t = threadIdx.x;
    int base = blockIdx.x * EPB;
    int eend = base + EPB; if (eend > N_EDGES) eend = N_EDGES;

    if (t < 128) cnt[t] = 0;
    __syncthreads();

    int d[4], sv[4];
    bool ok[4];
    #pragma unroll
    for (int i = 0; i < 4; ++i) {
        int e = base + t + i * 512;
        ok[i] = (e < eend);
        if (ok[i]) {
            d[i]  = clamp_node(ei[N_EDGES + e]);
            sv[i] = clamp_node(ei[e]);
            atomicAdd(&cnt[d[i] >> BSH], 1);
        }
    }
    __syncthreads();
    int v = (t < 128) ? cnt[t] : 0;
    s[t] = v;
    __syncthreads();
    for (int off = 1; off < 128; off <<= 1) {
        int y = (t >= off && t < 128) ? s[t - off] : 0;
        __syncthreads();
        if (t < 128) s[t] += y;
        __syncthreads();
    }
    if (t < 128) { ofs[t] = s[t] - v; cur[t] = s[t] - v; }
    __syncthreads();
    #pragma unroll
    for (int i = 0; i < 4; ++i) {
        if (ok[i]) {
            int b = d[i] >> BSH;
            int p = atomicAdd(&cur[b], 1);
            list[p] = (unsigned)sv[i] | ((unsigned)(d[i] & 511) << 16);
        }
    }
    __syncthreads();
    int wv = t >> 6, lane = t & 63;
    const int NGRP = 13;   // ceil(98/8)
    for (int jj = 0; jj < NGRP; ++jj) {
        int b = wv + 8 * ((jj + (int)blockIdx.x) % NGRP);
        if (b >= NB) continue;
        int c = cnt[b];
        if (c == 0) continue;
        int gpos;
        if (lane == 0) gpos = atomicAdd(&bcur[b * BPAD], c);
        gpos = __shfl(gpos, 0);
        int ls = ofs[b];
        for (int i = lane; i < c; i += 64) tmp[gpos + i] = list[ls + i];
    }
}

// ---------------------------------------------------------------------------
// Placement phase B: one block per bucket; scatter confined to the
// block-exclusive 32KB srcs region (full-line evicts).
// ---------------------------------------------------------------------------
__global__ __launch_bounds__(512) void k_place2(const unsigned* __restrict__ tmp,
                                                const int* __restrict__ rs,
                                                int* __restrict__ ncur,
                                                int* __restrict__ srcs) {
    int b   = blockIdx.x;
    int nlo = b << BSH;
    int nhi = nlo + 512; if (nhi > N_NODES) nhi = N_NODES;
    int estart = rs[nlo], eend = rs[nhi];
    for (int e = estart + (int)threadIdx.x; e < eend; e += 512) {
        unsigned val = tmp[e];
        int d = nlo + (int)(val >> 16);
        int pos = atomicAdd(&ncur[d], 1);
        srcs[pos] = (int)(val & 0xFFFFu);
    }
}

// ---------------------------------------------------------------------------
// Prep (one launch): f32->bf16 row-major feature convert + pack both concat
// weights [Wl;Wr]^T into MFMA fragment order.
// frag[(ot*8+ks)*64 + lane][j] = B[ks*32 + (lane>>4)*8 + j][ot*16 + (lane&15)]
// ---------------------------------------------------------------------------
__global__ __launch_bounds__(256) void k_prep(const float* __restrict__ x,
                                              unsigned short* __restrict__ xb,
                                              const float* __restrict__ W1l,
                                              const float* __restrict__ W1r,
                                              const float* __restrict__ W2l,
                                              const float* __restrict__ W2r,
                                              unsigned short* __restrict__ wbuf1,
                                              unsigned short* __restrict__ wbuf2) {
    int i = blockIdx.x * 256 + threadIdx.x;
    const int n8 = N_NODES * 16;            // 800000 8-elem conversions
    if (i < n8) {
        const float4* p = (const float4*)(x + (size_t)i * 8);
        float4 a = p[0], b = p[1];
        union { unsigned short s[8]; uint4 u; } o;
        o.s[0] = f2bf(a.x); o.s[1] = f2bf(a.y); o.s[2] = f2bf(a.z); o.s[3] = f2bf(a.w);
        o.s[4] = f2bf(b.x); o.s[5] = f2bf(b.y); o.s[6] = f2bf(b.z); o.s[7] = f2bf(b.w);
        *(uint4*)(xb + (size_t)i * 8) = o.u;
        return;
    }
    int tid = i - n8;
    if (tid >= 2 * 8 * 8 * 64) return;
    int which = tid >> 12;
    int id    = tid & 4095;
    const float* Wl = which ? W2l : W1l;
    const float* Wr = which ? W2r : W1r;
    unsigned short* wbuf = which ? wbuf2 : wbuf1;
    int lane = id & 63;
    int ks   = (id >> 6) & 7;
    int ot   = id >> 9;
    int o  = ot * 16 + (lane & 15);
    int kb = ks * 32 + ((lane >> 4) << 3);
    union { unsigned short s[8]; uint4 u; } frag;
    #pragma unroll
    for (int j = 0; j < 8; ++j) {
        int k = kb + j;
        float v = (k < DIM) ? Wl[o * DIM + k] : Wr[o * DIM + (k - DIM)];
        frag.s[j] = f2bf(v);
    }
    *(uint4*)(wbuf + (size_t)id * 8) = frag.u;
}

// ---------------------------------------------------------------------------
// FUSED SAGE layer: gather-mean (4 nodes/wave, 8x unroll) -> LDS tile ->
// MFMA dual-GEMM + bias + ReLU -> bf16 store. Block = 4 waves = 16 nodes.
// OCCUPANCY MODEL (r11/r12): gather is latency-bound; time scales inversely
// with the VGPR-set wave cap (80 VGPR/6 waves = 44.7us; 88/5 = 52.7us).
// So: NO register preloads across the gather. B-fragments are loaded inside
// the MFMA loop (wbuf is 8KB, L1/L2-hot) and __launch_bounds__(256,8) pins
// the allocator at 64 VGPR -> 8 waves/SIMD cap.
// Round-10 lesson: per-block dim-chunking desyncs across blocks; don't chunk.
// ---------------------------------------------------------------------------
__global__ __launch_bounds__(256, 8) void k_sage(const unsigned short* __restrict__ feat,
                                                 const unsigned short* __restrict__ in2b,
                                                 const int* __restrict__ rs,
                                                 const int* __restrict__ srcs,
                                                 const unsigned short* __restrict__ wbuf,
                                                 const float* __restrict__ bias,
                                                 unsigned short* __restrict__ outb) {
    __shared__ unsigned short almp[16][136];   // row stride 272B
    int t    = threadIdx.x;
    int wave = t >> 6;
    int lane = t & 63;
    int n0   = blockIdx.x * 16;

    // ---- phase 1: gather-mean; lane (q,sub) owns node q's 16B chunk sub ----
    {
        int q   = lane >> 4;
        int sub = lane & 15;
        int node  = n0 + wave * 4 + q;
        int start = rs[node];
        int end   = rs[node + 1];
        float a0 = 0.f, a1 = 0.f, a2 = 0.f, a3 = 0.f;
        float a4 = 0.f, a5 = 0.f, a6 = 0.f, a7 = 0.f;
        const size_t coff = (size_t)sub * 8;

#define ACC8(r) { a0 += bflo(r.x); a1 += bfhi(r.x); a2 += bflo(r.y); a3 += bfhi(r.y); \
                  a4 += bflo(r.z); a5 += bfhi(r.z); a6 += bflo(r.w); a7 += bfhi(r.w); }
        int e = start;
        for (; e + 8 <= end; e += 8) {
            uint4 r0 = *(const uint4*)(feat + (size_t)srcs[e + 0] * DIM + coff);
            uint4 r1 = *(const uint4*)(feat + (size_t)srcs[e + 1] * DIM + coff);
            uint4 r2 = *(const uint4*)(feat + (size_t)srcs[e + 2] * DIM + coff);
            uint4 r3 = *(const uint4*)(feat + (size_t)srcs[e + 3] * DIM + coff);
            uint4 r4 = *(const uint4*)(feat + (size_t)srcs[e + 4] * DIM + coff);
            uint4 r5 = *(const uint4*)(feat + (size_t)srcs[e + 5] * DIM + coff);
            uint4 r6 = *(const uint4*)(feat + (size_t)srcs[e + 6] * DIM + coff);
            uint4 r7 = *(const uint4*)(feat + (size_t)srcs[e + 7] * DIM + coff);
            ACC8(r0) ACC8(r1) ACC8(r2) ACC8(r3) ACC8(r4) ACC8(r5) ACC8(r6) ACC8(r7)
        }
        for (; e + 2 <= end; e += 2) {
            uint4 r0 = *(const uint4*)(feat + (size_t)srcs[e + 0] * DIM + coff);
            uint4 r1 = *(const uint4*)(feat + (size_t)srcs[e + 1] * DIM + coff);
            ACC8(r0) ACC8(r1)
        }
        if (e < end) {
            uint4 r0 = *(const uint4*)(feat + (size_t)srcs[e] * DIM + coff);
            ACC8(r0)
        }
#undef ACC8
        float inv = 1.0f / fmaxf((float)(end - start), 1.0f);
        union { unsigned short s[8]; uint4 u; } o;
        o.s[0] = f2bf(a0 * inv); o.s[1] = f2bf(a1 * inv);
        o.s[2] = f2bf(a2 * inv); o.s[3] = f2bf(a3 * inv);
        o.s[4] = f2bf(a4 * inv); o.s[5] = f2bf(a5 * inv);
        o.s[6] = f2bf(a6 * inv); o.s[7] = f2bf(a7 * inv);
        *(uint4*)&almp[wave * 4 + q][sub * 8] = o.u;
    }
    __syncthreads();

    // ---- phase 2: MFMA (B-frags loaded per k-step from hot wbuf) ----
    int row = lane & 15;
    int kl  = (lane >> 4) << 3;
    bf16x8 A[8];
    #pragma unroll
    for (int ks = 0; ks < 4; ++ks)
        A[ks] = *(const bf16x8*)&almp[row][kl + ks * 32];
    const unsigned short* xrow = in2b + (size_t)(n0 + row) * DIM + kl;
    #pragma unroll
    for (int ks = 0; ks < 4; ++ks)
        A[4 + ks] = *(const bf16x8*)(xrow + ks * 32);

    const unsigned short* wb0 = wbuf + ((size_t)(wave * 2)     * 8 * 64 + lane) * 8;
    const unsigned short* wb1 = wbuf + ((size_t)(wave * 2 + 1) * 8 * 64 + lane) * 8;
    f32x4 acc0 = {0.f, 0.f, 0.f, 0.f}, acc1 = {0.f, 0.f, 0.f, 0.f};
    #pragma unroll
    for (int ks = 0; ks < 8; ++ks) {
        bf16x8 b0 = *(const bf16x8*)(wb0 + (size_t)ks * 64 * 8);
        bf16x8 b1 = *(const bf16x8*)(wb1 + (size_t)ks * 64 * 8);
        acc0 = __builtin_amdgcn_mfma_f32_16x16x32_bf16(A[ks], b0, acc0, 0, 0, 0);
        acc1 = __builtin_amdgcn_mfma_f32_16x16x32_bf16(A[ks], b1, acc1, 0, 0, 0);
    }

    // C/D layout: col = lane&15, row = (lane>>4)*4 + reg   [m89-verified]
    int o0   = wave * 32;
    int ocol = lane & 15;
    int rb   = (lane >> 4) << 2;
    float b0 = bias[o0 + ocol];
    float b1 = bias[o0 + 16 + ocol];
    #pragma unroll
    for (int r = 0; r < 4; ++r) {
        size_t n = (size_t)(n0 + rb + r);
        outb[n * DIM + o0 + ocol]      = f2bf(fmaxf(acc0[r] + b0, 0.f));
        outb[n * DIM + o0 + 16 + ocol] = f2bf(fmaxf(acc1[r] + b1, 0.f));
    }
}

// ---------------------------------------------------------------------------
// Pool stage 1: partial per-graph sums (batch sorted; flush on graph change).
// ---------------------------------------------------------------------------
__global__ __launch_bounds__(256) void k_pool_partial(const unsigned short* __restrict__ h2,
                                                      const int* __restrict__ batch,
                                                      float* __restrict__ gsum) {
    int wid  = (blockIdx.x * 256 + threadIdx.x) >> 6;
    int lane = threadIdx.x & 63;
    int n0 = wid * 32;
    if (n0 >= N_NODES) return;
    int n1 = n0 + 32; if (n1 > N_NODES) n1 = N_NODES;
    int col = lane * 2;

    float ax = 0.f, ay = 0.f;
    int cur = batch[n0];
    for (int n = n0; n < n1; ++n) {
        int b = batch[n];
        if (b != cur) {
            atomicAdd(&gsum[cur * DIM + col], ax);
            atomicAdd(&gsum[cur * DIM + col + 1], ay);
            ax = 0.f; ay = 0.f; cur = b;
        }
        unsigned u = *(const unsigned*)(h2 + (size_t)n * DIM + col);
        ax += bflo(u); ay += bfhi(u);
    }
    atomicAdd(&gsum[cur * DIM + col], ax);
    atomicAdd(&gsum[cur * DIM + col + 1], ay);
}

// ---------------------------------------------------------------------------
// Pool stage 2: mean + MLP head. One block per graph.
// ---------------------------------------------------------------------------
__global__ __launch_bounds__(256) void k_head(const float* __restrict__ gsum,
                                              const int* __restrict__ batch,
                                              const float* __restrict__ wl1,
                                              const float* __restrict__ bl1,
                                              const float* __restrict__ wout,
                                              const float* __restrict__ bout,
                                              float* __restrict__ out) {
    int g = blockIdx.x;
    int t = threadIdx.x;

    int lo = 0, hi = N_NODES;
    while (lo < hi) { int mid = (lo + hi) >> 1; if (batch[mid] < g) lo = mid + 1; else hi = mid; }
    int s = lo;
    lo = 0; hi = N_NODES;
    while (lo < hi) { int mid = (lo + hi) >> 1; if (batch[mid] < g + 1) lo = mid + 1; else hi = mid; }
    int e = lo;

    __shared__ float gvec[DIM];
    if (t < DIM) {
        float cnt = fmaxf((float)(e - s), 1.0f);
        gvec[t] = gsum[g * DIM + t] / cnt;
    }
    __syncthreads();
    if (t < 64) {
        float a = bl1[t];
        #pragma unroll 4
        for (int k = 0; k < DIM; ++k) a += wl1[t * DIM + k] * gvec[k];
        float g1 = fmaxf(a, 0.f) * wout[t];
        #pragma unroll
        for (int off = 32; off > 0; off >>= 1) g1 += __shfl_down(g1, off);
        if (t == 0) {
            float z = g1 + bout[0];
            out[g] = 1.0f / (1.0f + expf(-z));
        }
    }
}

// ---------------------------------------------------------------------------
extern "C" void kernel_launch(void* const* d_in, const int* in_sizes, int n_in,
                              void* d_out, int out_size, void* d_ws, size_t ws_size,
                              hipStream_t stream) {
    const float* x     = (const float*)d_in[0];
    const int*   ei    = (const int*)d_in[1];    // int64 in ref -> int32 here
    const int*   batch = (const int*)d_in[2];
    const float* w1l   = (const float*)d_in[3];
    const float* b1l   = (const float*)d_in[4];
    const float* w1r   = (const float*)d_in[5];
    const float* w2l   = (const float*)d_in[6];
    const float* b2l   = (const float*)d_in[7];
    const float* w2r   = (const float*)d_in[8];
    const float* wl1   = (const float*)d_in[9];
    const float* bl1   = (const float*)d_in[10];
    const float* wout  = (const float*)d_in[11];
    const float* bout  = (const float*)d_in[12];
    float* out = (float*)d_out;

    char*  wsp = (char*)d_ws;
    size_t off = 0;
    auto alloc = [&](size_t bytes) -> char* {
        char* p = wsp + off;
        off += (bytes + 255) & ~(size_t)255;
        return p;
    };
    int* rs   = (int*)alloc((size_t)(N_NODES + 1) * 4);
    int* ncur = (int*)alloc((size_t)N_NODES * 4);
    int* hist = (int*)alloc((size_t)N_NODES * 4);
    int* bsum = (int*)alloc(256 * 4);
    int* bcur = (int*)alloc((size_t)NB * BPAD * 4);
    int* srcs = (int*)alloc((size_t)N_EDGES * 4);
    unsigned* tmp = (unsigned*)alloc((size_t)N_EDGES * 4);
    unsigned short* xb    = (unsigned short*)alloc((size_t)N_NODES * DIM * 2);
    unsigned short* h1b   = (unsigned short*)alloc((size_t)N_NODES * DIM * 2);
    unsigned short* h2b   = (unsigned short*)alloc((size_t)N_NODES * DIM * 2);
    unsigned short* wbuf1 = (unsigned short*)alloc((size_t)8 * 8 * 64 * 8 * 2);
    unsigned short* wbuf2 = (unsigned short*)alloc((size_t)8 * 8 * 64 * 8 * 2);
    float* gsum = (float*)alloc((size_t)N_GRAPHS * DIM * 4);

    const int nb = (N_NODES + 511) / 512;   // 98

    hipMemsetAsync(hist, 0, (size_t)N_NODES * 4, stream);
    hipMemsetAsync(gsum, 0, (size_t)N_GRAPHS * DIM * 4, stream);
    k_hist<<<(N_EDGES + 255) / 256, 256, 0, stream>>>(ei, hist);
    k_blocksum<<<nb, 256, 0, stream>>>(hist, bsum);
    k_scan_bsum<<<1, 64, 0, stream>>>(bsum, nb, bcur);
    k_scan_write<<<nb, 512, 0, stream>>>(hist, bsum, rs, ncur);
    k_bucket<<<(N_EDGES + EPB - 1) / EPB, 512, 0, stream>>>(ei, bcur, tmp);
    k_place2<<<NB, 512, 0, stream>>>(tmp, rs, ncur, srcs);

    // dtype prep (single launch: feature convert + both weight packs)
    k_prep<<<(N_NODES * 16 + 2 * 8 * 8 * 64 + 255) / 256, 256, 0, stream>>>(
        x, xb, w1l, w1r, w2l, w2r, wbuf1, wbuf2);

    // conv1 (fused aggregate + GEMM)
    k_sage<<<N_NODES / 16, 256, 0, stream>>>(xb, xb, rs, srcs, wbuf1, b1l, h1b);
    // conv2
    k_sage<<<N_NODES / 16, 256, 0, stream>>>(h1b, h1b, rs, srcs, wbuf2, b2l, h2b);
    // pool (2-stage) + head
    k_pool_partial<<<(N_NODES + 127) / 128, 256, 0, stream>>>(h2b, batch, gsum);
    k_head<<<N_GRAPHS, 256, 0, stream>>>(gsum, batch, wl1, bl1, wout, bout, out);
}

// Round 14
// 157.971 us; speedup vs baseline: 1.5905x; 1.5905x over previous
//
#include <hip/hip_runtime.h>
#include <cstdint>
#include <cstddef>

#define N_NODES  50000
#define N_EDGES  800000
#define DIM      128
#define N_GRAPHS 64
#define NB       98        // coarse buckets of 512 nodes
#define BSH      9
#define EPB      2048      // edges per k_bucket block
#define BPAD     16        // bcur padding: one counter per 64B line
#define CAP      16384     // per-bucket region capacity (max bucket ~8.5K)

typedef __attribute__((ext_vector_type(8))) short     bf16x8;
typedef __attribute__((ext_vector_type(4))) float     f32x4;

__device__ __forceinline__ int clamp_node(int v) {
    return v < 0 ? 0 : (v >= N_NODES ? N_NODES - 1 : v);
}
__device__ __forceinline__ unsigned short f2bf(float f) {
    union { float f; unsigned u; } v; v.f = f;
    unsigned r = v.u + 0x7FFF + ((v.u >> 16) & 1);   // round-to-nearest-even
    return (unsigned short)(r >> 16);
}
__device__ __forceinline__ float bflo(unsigned u) {
    union { unsigned u; float f; } v; v.u = u << 16; return v.f;
}
__device__ __forceinline__ float bfhi(unsigned u) {
    union { unsigned u; float f; } v; v.u = u & 0xFFFF0000u; return v.f;
}

// ---------------------------------------------------------------------------
// Placement phase A: 391 blocks x 2048 edges; LDS counting sort into 98
// coarse buckets (dst>>9); bulk-append runs into FIXED per-bucket regions
// tmp[b*CAP ...] (bcur zero-based -> no global CSR prefix needed; this
// deleted the whole hist/scan chain). bcur line-padded + blockIdx-staggered
// flush (round-7 lesson: same-line cursor convoy).
// Packed entry: src (16b) | dst_local (9b) << 16.
// ---------------------------------------------------------------------------
__global__ __launch_bounds__(512) void k_bucket(const int* __restrict__ ei,
                                                int* __restrict__ bcur,
                                                unsigned* __restrict__ tmp) {
    __shared__ int cnt[128], cur[128], ofs[128];
    __shared__ int s[512];
    __shared__ unsigned list[EPB];
    int t = threadIdx.x;
    int base = blockIdx.x * EPB;
    int eend = base + EPB; if (eend > N_EDGES) eend = N_EDGES;

    if (t < 128) cnt[t] = 0;
    __syncthreads();

    int d[4], sv[4];
    bool ok[4];
    #pragma unroll
    for (int i = 0; i < 4; ++i) {
        int e = base + t + i * 512;
        ok[i] = (e < eend);
        if (ok[i]) {
            d[i]  = clamp_node(ei[N_EDGES + e]);
            sv[i] = clamp_node(ei[e]);
            atomicAdd(&cnt[d[i] >> BSH], 1);
        }
    }
    __syncthreads();
    int v = (t < 128) ? cnt[t] : 0;
    s[t] = v;
    __syncthreads();
    for (int off = 1; off < 128; off <<= 1) {
        int y = (t >= off && t < 128) ? s[t - off] : 0;
        __syncthreads();
        if (t < 128) s[t] += y;
        __syncthreads();
    }
    if (t < 128) { ofs[t] = s[t] - v; cur[t] = s[t] - v; }
    __syncthreads();
    #pragma unroll
    for (int i = 0; i < 4; ++i) {
        if (ok[i]) {
            int b = d[i] >> BSH;
            int p = atomicAdd(&cur[b], 1);
            list[p] = (unsigned)sv[i] | ((unsigned)(d[i] & 511) << 16);
        }
    }
    __syncthreads();
    int wv = t >> 6, lane = t & 63;
    const int NGRP = 13;   // ceil(98/8)
    for (int jj = 0; jj < NGRP; ++jj) {
        int b = wv + 8 * ((jj + (int)blockIdx.x) % NGRP);
        if (b >= NB) continue;
        int c = cnt[b];
        if (c == 0) continue;
        int gpos;
        if (lane == 0) gpos = atomicAdd(&bcur[b * BPAD], c);
        gpos = __shfl(gpos, 0);
        if (gpos + c > CAP) c = (gpos < CAP) ? (CAP - gpos) : 0;  // defensive
        int ls = ofs[b];
        for (int i = lane; i < c; i += 64) tmp[b * CAP + gpos + i] = list[ls + i];
    }
}

// ---------------------------------------------------------------------------
// Local CSR build: one block per bucket. LDS 512-node histogram over the
// bucket run -> in-block scan -> per-node {start,end} (rsse, int2) -> scatter
// srcs into node order within the bucket's exclusive region (full-line
// evicts). Replaces the old global hist/scan/place chain entirely.
// ---------------------------------------------------------------------------
__global__ __launch_bounds__(512) void k_csr(const unsigned* __restrict__ tmp,
                                             const int* __restrict__ bcur,
                                             int2* __restrict__ rsse,
                                             int* __restrict__ srcs) {
    __shared__ int lh[512], lcur[512];
    __shared__ int s[512];
    int b = blockIdx.x;
    int t = threadIdx.x;
    int base = b * CAP;
    int nc = bcur[b * BPAD];
    if (nc > CAP) nc = CAP;

    lh[t] = 0;
    __syncthreads();
    for (int e = t; e < nc; e += 512)
        atomicAdd(&lh[tmp[base + e] >> 16], 1);
    __syncthreads();
    int v = lh[t];
    s[t] = v;
    __syncthreads();
    for (int off = 1; off < 512; off <<= 1) {
        int y = (t >= off) ? s[t - off] : 0;
        __syncthreads();
        s[t] += y;
        __syncthreads();
    }
    int st = s[t] - v;                 // exclusive local start
    lcur[t] = st;
    int node = (b << BSH) + t;
    if (node < N_NODES) rsse[node] = make_int2(base + st, base + st + v);
    __syncthreads();
    for (int e = t; e < nc; e += 512) {
        unsigned val = tmp[base + e];
        int pos = atomicAdd(&lcur[val >> 16], 1);
        srcs[base + pos] = (int)(val & 0xFFFFu);
    }
}

// ---------------------------------------------------------------------------
// Prep (one launch): f32->bf16 row-major feature convert + pack both concat
// weights [Wl;Wr]^T into MFMA fragment order.
// frag[(ot*8+ks)*64 + lane][j] = B[ks*32 + (lane>>4)*8 + j][ot*16 + (lane&15)]
// ---------------------------------------------------------------------------
__global__ __launch_bounds__(256) void k_prep(const float* __restrict__ x,
                                              unsigned short* __restrict__ xb,
                                              const float* __restrict__ W1l,
                                              const float* __restrict__ W1r,
                                              const float* __restrict__ W2l,
                                              const float* __restrict__ W2r,
                                              unsigned short* __restrict__ wbuf1,
                                              unsigned short* __restrict__ wbuf2) {
    int i = blockIdx.x * 256 + threadIdx.x;
    const int n8 = N_NODES * 16;            // 800000 8-elem conversions
    if (i < n8) {
        const float4* p = (const float4*)(x + (size_t)i * 8);
        float4 a = p[0], b = p[1];
        union { unsigned short s[8]; uint4 u; } o;
        o.s[0] = f2bf(a.x); o.s[1] = f2bf(a.y); o.s[2] = f2bf(a.z); o.s[3] = f2bf(a.w);
        o.s[4] = f2bf(b.x); o.s[5] = f2bf(b.y); o.s[6] = f2bf(b.z); o.s[7] = f2bf(b.w);
        *(uint4*)(xb + (size_t)i * 8) = o.u;
        return;
    }
    int tid = i - n8;
    if (tid >= 2 * 8 * 8 * 64) return;
    int which = tid >> 12;
    int id    = tid & 4095;
    const float* Wl = which ? W2l : W1l;
    const float* Wr = which ? W2r : W1r;
    unsigned short* wbuf = which ? wbuf2 : wbuf1;
    int lane = id & 63;
    int ks   = (id >> 6) & 7;
    int ot   = id >> 9;
    int o  = ot * 16 + (lane & 15);
    int kb = ks * 32 + ((lane >> 4) << 3);
    union { unsigned short s[8]; uint4 u; } frag;
    #pragma unroll
    for (int j = 0; j < 8; ++j) {
        int k = kb + j;
        float v = (k < DIM) ? Wl[o * DIM + k] : Wr[o * DIM + (k - DIM)];
        frag.s[j] = f2bf(v);
    }
    *(uint4*)(wbuf + (size_t)id * 8) = frag.u;
}

// ---------------------------------------------------------------------------
// FUSED SAGE layer — FROZEN r12 form (44.7us, VGPR 80, proven optimum of the
// outstanding-loads x occupancy trade-off; r10/r11/r13 all lost):
// gather-mean (4 nodes/wave, 8x unroll) -> LDS tile -> MFMA dual-GEMM +
// bias + ReLU -> bf16 store. Block = 4 waves = 16 nodes. B-frags preloaded
// before the gather; root A-frags after the barrier. Only change vs r12:
// per-node extent comes from rsse (int2 {start,end}) instead of rs/rs+1.
// ---------------------------------------------------------------------------
__global__ __launch_bounds__(256) void k_sage(const unsigned short* __restrict__ feat,
                                              const unsigned short* __restrict__ in2b,
                                              const int2* __restrict__ rsse,
                                              const int* __restrict__ srcs,
                                              const unsigned short* __restrict__ wbuf,
                                              const float* __restrict__ bias,
                                              unsigned short* __restrict__ outb) {
    __shared__ unsigned short almp[16][136];   // row stride 272B
    int t    = threadIdx.x;
    int wave = t >> 6;
    int lane = t & 63;
    int n0   = blockIdx.x * 16;

    // B fragments (independent; scheduler hides them under the gather)
    bf16x8 B[2][8];
    #pragma unroll
    for (int ot = 0; ot < 2; ++ot)
        #pragma unroll
        for (int ks = 0; ks < 8; ++ks)
            B[ot][ks] = *(const bf16x8*)(wbuf +
                (((size_t)(wave * 2 + ot) * 8 + ks) * 64 + lane) * 8);

    // ---- phase 1: gather-mean; lane (q,sub) owns node q's 16B chunk sub ----
    {
        int q   = lane >> 4;
        int sub = lane & 15;
        int node  = n0 + wave * 4 + q;
        int2 se   = rsse[node];
        int start = se.x;
        int end   = se.y;
        float a0 = 0.f, a1 = 0.f, a2 = 0.f, a3 = 0.f;
        float a4 = 0.f, a5 = 0.f, a6 = 0.f, a7 = 0.f;
        const size_t coff = (size_t)sub * 8;

#define ACC8(r) { a0 += bflo(r.x); a1 += bfhi(r.x); a2 += bflo(r.y); a3 += bfhi(r.y); \
                  a4 += bflo(r.z); a5 += bfhi(r.z); a6 += bflo(r.w); a7 += bfhi(r.w); }
        int e = start;
        for (; e + 8 <= end; e += 8) {
            uint4 r0 = *(const uint4*)(feat + (size_t)srcs[e + 0] * DIM + coff);
            uint4 r1 = *(const uint4*)(feat + (size_t)srcs[e + 1] * DIM + coff);
            uint4 r2 = *(const uint4*)(feat + (size_t)srcs[e + 2] * DIM + coff);
            uint4 r3 = *(const uint4*)(feat + (size_t)srcs[e + 3] * DIM + coff);
            uint4 r4 = *(const uint4*)(feat + (size_t)srcs[e + 4] * DIM + coff);
            uint4 r5 = *(const uint4*)(feat + (size_t)srcs[e + 5] * DIM + coff);
            uint4 r6 = *(const uint4*)(feat + (size_t)srcs[e + 6] * DIM + coff);
            uint4 r7 = *(const uint4*)(feat + (size_t)srcs[e + 7] * DIM + coff);
            ACC8(r0) ACC8(r1) ACC8(r2) ACC8(r3) ACC8(r4) ACC8(r5) ACC8(r6) ACC8(r7)
        }
        for (; e + 2 <= end; e += 2) {
            uint4 r0 = *(const uint4*)(feat + (size_t)srcs[e + 0] * DIM + coff);
            uint4 r1 = *(const uint4*)(feat + (size_t)srcs[e + 1] * DIM + coff);
            ACC8(r0) ACC8(r1)
        }
        if (e < end) {
            uint4 r0 = *(const uint4*)(feat + (size_t)srcs[e] * DIM + coff);
            ACC8(r0)
        }
#undef ACC8
        float inv = 1.0f / fmaxf((float)(end - start), 1.0f);
        union { unsigned short s[8]; uint4 u; } o;
        o.s[0] = f2bf(a0 * inv); o.s[1] = f2bf(a1 * inv);
        o.s[2] = f2bf(a2 * inv); o.s[3] = f2bf(a3 * inv);
        o.s[4] = f2bf(a4 * inv); o.s[5] = f2bf(a5 * inv);
        o.s[6] = f2bf(a6 * inv); o.s[7] = f2bf(a7 * inv);
        *(uint4*)&almp[wave * 4 + q][sub * 8] = o.u;
    }
    __syncthreads();

    // ---- phase 2: MFMA ----
    int row = lane & 15;
    int kl  = (lane >> 4) << 3;
    bf16x8 A[8];
    #pragma unroll
    for (int ks = 0; ks < 4; ++ks)
        A[ks] = *(const bf16x8*)&almp[row][kl + ks * 32];
    const unsigned short* xrow = in2b + (size_t)(n0 + row) * DIM + kl;
    #pragma unroll
    for (int ks = 0; ks < 4; ++ks)
        A[4 + ks] = *(const bf16x8*)(xrow + ks * 32);

    f32x4 acc0 = {0.f, 0.f, 0.f, 0.f}, acc1 = {0.f, 0.f, 0.f, 0.f};
    #pragma unroll
    for (int ks = 0; ks < 8; ++ks) {
        acc0 = __builtin_amdgcn_mfma_f32_16x16x32_bf16(A[ks], B[0][ks], acc0, 0, 0, 0);
        acc1 = __builtin_amdgcn_mfma_f32_16x16x32_bf16(A[ks], B[1][ks], acc1, 0, 0, 0);
    }

    // C/D layout: col = lane&15, row = (lane>>4)*4 + reg   [m89-verified]
    int o0   = wave * 32;
    int ocol = lane & 15;
    int rb   = (lane >> 4) << 2;
    float b0 = bias[o0 + ocol];
    float b1 = bias[o0 + 16 + ocol];
    #pragma unroll
    for (int r = 0; r < 4; ++r) {
        size_t n = (size_t)(n0 + rb + r);
        outb[n * DIM + o0 + ocol]      = f2bf(fmaxf(acc0[r] + b0, 0.f));
        outb[n * DIM + o0 + 16 + ocol] = f2bf(fmaxf(acc1[r] + b1, 0.f));
    }
}

// ---------------------------------------------------------------------------
// Pool stage 1: partial per-graph sums (batch sorted; flush on graph change).
// ---------------------------------------------------------------------------
__global__ __launch_bounds__(256) void k_pool_partial(const unsigned short* __restrict__ h2,
                                                      const int* __restrict__ batch,
                                                      float* __restrict__ gsum) {
    int wid  = (blockIdx.x * 256 + threadIdx.x) >> 6;
    int lane = threadIdx.x & 63;
    int n0 = wid * 32;
    if (n0 >= N_NODES) return;
    int n1 = n0 + 32; if (n1 > N_NODES) n1 = N_NODES;
    int col = lane * 2;

    float ax = 0.f, ay = 0.f;
    int cur = batch[n0];
    for (int n = n0; n < n1; ++n) {
        int b = batch[n];
        if (b != cur) {
            atomicAdd(&gsum[cur * DIM + col], ax);
            atomicAdd(&gsum[cur * DIM + col + 1], ay);
            ax = 0.f; ay = 0.f; cur = b;
        }
        unsigned u = *(const unsigned*)(h2 + (size_t)n * DIM + col);
        ax += bflo(u); ay += bfhi(u);
    }
    atomicAdd(&gsum[cur * DIM + col], ax);
    atomicAdd(&gsum[cur * DIM + col + 1], ay);
}

// ---------------------------------------------------------------------------
// Pool stage 2: mean + MLP head. One block per graph.
// ---------------------------------------------------------------------------
__global__ __launch_bounds__(256) void k_head(const float* __restrict__ gsum,
                                              const int* __restrict__ batch,
                                              const float* __restrict__ wl1,
                                              const float* __restrict__ bl1,
                                              const float* __restrict__ wout,
                                              const float* __restrict__ bout,
                                              float* __restrict__ out) {
    int g = blockIdx.x;
    int t = threadIdx.x;

    int lo = 0, hi = N_NODES;
    while (lo < hi) { int mid = (lo + hi) >> 1; if (batch[mid] < g) lo = mid + 1; else hi = mid; }
    int s = lo;
    lo = 0; hi = N_NODES;
    while (lo < hi) { int mid = (lo + hi) >> 1; if (batch[mid] < g + 1) lo = mid + 1; else hi = mid; }
    int e = lo;

    __shared__ float gvec[DIM];
    if (t < DIM) {
        float cnt = fmaxf((float)(e - s), 1.0f);
        gvec[t] = gsum[g * DIM + t] / cnt;
    }
    __syncthreads();
    if (t < 64) {
        float a = bl1[t];
        #pragma unroll 4
        for (int k = 0; k < DIM; ++k) a += wl1[t * DIM + k] * gvec[k];
        float g1 = fmaxf(a, 0.f) * wout[t];
        #pragma unroll
        for (int off = 32; off > 0; off >>= 1) g1 += __shfl_down(g1, off);
        if (t == 0) {
            float z = g1 + bout[0];
            out[g] = 1.0f / (1.0f + expf(-z));
        }
    }
}

// ---------------------------------------------------------------------------
extern "C" void kernel_launch(void* const* d_in, const int* in_sizes, int n_in,
                              void* d_out, int out_size, void* d_ws, size_t ws_size,
                              hipStream_t stream) {
    const float* x     = (const float*)d_in[0];
    const int*   ei    = (const int*)d_in[1];    // int64 in ref -> int32 here
    const int*   batch = (const int*)d_in[2];
    const float* w1l   = (const float*)d_in[3];
    const float* b1l   = (const float*)d_in[4];
    const float* w1r   = (const float*)d_in[5];
    const float* w2l   = (const float*)d_in[6];
    const float* b2l   = (const float*)d_in[7];
    const float* w2r   = (const float*)d_in[8];
    const float* wl1   = (const float*)d_in[9];
    const float* bl1   = (const float*)d_in[10];
    const float* wout  = (const float*)d_in[11];
    const float* bout  = (const float*)d_in[12];
    float* out = (float*)d_out;

    char*  wsp = (char*)d_ws;
    size_t off = 0;
    auto alloc = [&](size_t bytes) -> char* {
        char* p = wsp + off;
        off += (bytes + 255) & ~(size_t)255;
        return p;
    };
    int*  bcur = (int*)alloc((size_t)NB * BPAD * 4);
    int2* rsse = (int2*)alloc((size_t)N_NODES * 8);
    int*  srcs = (int*)alloc((size_t)NB * CAP * 4);
    unsigned* tmp = (unsigned*)alloc((size_t)NB * CAP * 4);
    unsigned short* xb    = (unsigned short*)alloc((size_t)N_NODES * DIM * 2);
    unsigned short* h1b   = (unsigned short*)alloc((size_t)N_NODES * DIM * 2);
    unsigned short* h2b   = (unsigned short*)alloc((size_t)N_NODES * DIM * 2);
    unsigned short* wbuf1 = (unsigned short*)alloc((size_t)8 * 8 * 64 * 8 * 2);
    unsigned short* wbuf2 = (unsigned short*)alloc((size_t)8 * 8 * 64 * 8 * 2);
    float* gsum = (float*)alloc((size_t)N_GRAPHS * DIM * 4);

    hipMemsetAsync(bcur, 0, (size_t)NB * BPAD * 4, stream);
    hipMemsetAsync(gsum, 0, (size_t)N_GRAPHS * DIM * 4, stream);

    // edge bucketing -> local CSR (no global hist/scan chain)
    k_bucket<<<(N_EDGES + EPB - 1) / EPB, 512, 0, stream>>>(ei, bcur, tmp);
    k_csr<<<NB, 512, 0, stream>>>(tmp, bcur, rsse, srcs);

    // dtype prep (single launch: feature convert + both weight packs)
    k_prep<<<(N_NODES * 16 + 2 * 8 * 8 * 64 + 255) / 256, 256, 0, stream>>>(
        x, xb, w1l, w1r, w2l, w2r, wbuf1, wbuf2);

    // conv1 (fused aggregate + GEMM)
    k_sage<<<N_NODES / 16, 256, 0, stream>>>(xb, xb, rsse, srcs, wbuf1, b1l, h1b);
    // conv2
    k_sage<<<N_NODES / 16, 256, 0, stream>>>(h1b, h1b, rsse, srcs, wbuf2, b2l, h2b);
    // pool (2-stage) + head
    k_pool_partial<<<(N_NODES + 127) / 128, 256, 0, stream>>>(h2b, batch, gsum);
    k_head<<<N_GRAPHS, 256, 0, stream>>>(gsum, batch, wl1, bl1, wout, bout, out);
}

// Round 15
// 157.686 us; speedup vs baseline: 1.5933x; 1.0018x over previous
//
#include <hip/hip_runtime.h>
#include <cstdint>
#include <cstddef>

#define N_NODES  50000
#define N_EDGES  800000
#define DIM      128
#define N_GRAPHS 64
#define NB       196       // coarse buckets of 256 nodes
#define BSH      8
#define EPB      2048      // edges per k_bucket block
#define BPAD     16        // bcur padding: one counter per 64B line
#define CAP      8192      // per-bucket region capacity (mean 4096, +6sigma ~4.5K)

typedef __attribute__((ext_vector_type(8))) short     bf16x8;
typedef __attribute__((ext_vector_type(4))) float     f32x4;

__device__ __forceinline__ int clamp_node(int v) {
    return v < 0 ? 0 : (v >= N_NODES ? N_NODES - 1 : v);
}
__device__ __forceinline__ unsigned short f2bf(float f) {
    union { float f; unsigned u; } v; v.f = f;
    unsigned r = v.u + 0x7FFF + ((v.u >> 16) & 1);   // round-to-nearest-even
    return (unsigned short)(r >> 16);
}
__device__ __forceinline__ float bflo(unsigned u) {
    union { unsigned u; float f; } v; v.u = u << 16; return v.f;
}
__device__ __forceinline__ float bfhi(unsigned u) {
    union { unsigned u; float f; } v; v.u = u & 0xFFFF0000u; return v.f;
}

// ---------------------------------------------------------------------------
// Placement phase A: 391 blocks x 2048 edges; LDS counting sort into 196
// coarse buckets (dst>>8); bulk-append runs into FIXED per-bucket regions
// tmp[b*CAP ...]. bcur line-padded + blockIdx-staggered flush (r7 lesson).
// Packed entry: src (16b) | dst_local (8b) << 16.
// ---------------------------------------------------------------------------
__global__ __launch_bounds__(512) void k_bucket(const int* __restrict__ ei,
                                                int* __restrict__ bcur,
                                                unsigned* __restrict__ tmp) {
    __shared__ int cnt[256], cur[256], ofs[256];
    __shared__ int s[512];
    __shared__ unsigned list[EPB];
    int t = threadIdx.x;
    int base = blockIdx.x * EPB;
    int eend = base + EPB; if (eend > N_EDGES) eend = N_EDGES;

    if (t < 256) cnt[t] = 0;
    __syncthreads();

    int d[4], sv[4];
    bool ok[4];
    #pragma unroll
    for (int i = 0; i < 4; ++i) {
        int e = base + t + i * 512;
        ok[i] = (e < eend);
        if (ok[i]) {
            d[i]  = clamp_node(ei[N_EDGES + e]);
            sv[i] = clamp_node(ei[e]);
            atomicAdd(&cnt[d[i] >> BSH], 1);
        }
    }
    __syncthreads();
    int v = (t < 256) ? cnt[t] : 0;
    s[t] = v;
    __syncthreads();
    for (int off = 1; off < 256; off <<= 1) {
        int y = (t >= off && t < 256) ? s[t - off] : 0;
        __syncthreads();
        if (t < 256) s[t] += y;
        __syncthreads();
    }
    if (t < 256) { ofs[t] = s[t] - v; cur[t] = s[t] - v; }
    __syncthreads();
    #pragma unroll
    for (int i = 0; i < 4; ++i) {
        if (ok[i]) {
            int b = d[i] >> BSH;
            int p = atomicAdd(&cur[b], 1);
            list[p] = (unsigned)sv[i] | ((unsigned)(d[i] & 255) << 16);
        }
    }
    __syncthreads();
    int wv = t >> 6, lane = t & 63;
    const int NGRP = 25;   // ceil(196/8)
    for (int jj = 0; jj < NGRP; ++jj) {
        int b = wv + 8 * ((jj + (int)blockIdx.x) % NGRP);
        if (b >= NB) continue;
        int c = cnt[b];
        if (c == 0) continue;
        int gpos;
        if (lane == 0) gpos = atomicAdd(&bcur[b * BPAD], c);
        gpos = __shfl(gpos, 0);
        if (gpos + c > CAP) c = (gpos < CAP) ? (CAP - gpos) : 0;  // defensive
        int ls = ofs[b];
        for (int i = lane; i < c; i += 64) tmp[b * CAP + gpos + i] = list[ls + i];
    }
}

// ---------------------------------------------------------------------------
// Local CSR build: one block per bucket (196 blocks — r14's 98 starved CUs).
// LDS 256-node histogram over the bucket run -> scan -> per-node {start,end}
// (rsse, int2) -> scatter srcs into node order within the bucket's exclusive
// region (full-line evicts).
// ---------------------------------------------------------------------------
__global__ __launch_bounds__(512) void k_csr(const unsigned* __restrict__ tmp,
                                             const int* __restrict__ bcur,
                                             int2* __restrict__ rsse,
                                             int* __restrict__ srcs) {
    __shared__ int lh[256], lcur[256];
    __shared__ int s[512];
    int b = blockIdx.x;
    int t = threadIdx.x;
    int base = b * CAP;
    int nc = bcur[b * BPAD];
    if (nc > CAP) nc = CAP;

    if (t < 256) lh[t] = 0;
    __syncthreads();
    for (int e = t; e < nc; e += 512)
        atomicAdd(&lh[tmp[base + e] >> 16], 1);
    __syncthreads();
    int v = (t < 256) ? lh[t] : 0;
    s[t] = v;
    __syncthreads();
    for (int off = 1; off < 256; off <<= 1) {
        int y = (t >= off && t < 256) ? s[t - off] : 0;
        __syncthreads();
        if (t < 256) s[t] += y;
        __syncthreads();
    }
    if (t < 256) {
        int st = s[t] - v;                 // exclusive local start
        lcur[t] = st;
        int node = (b << BSH) + t;
        if (node < N_NODES) rsse[node] = make_int2(base + st, base + st + v);
    }
    __syncthreads();
    for (int e = t; e < nc; e += 512) {
        unsigned val = tmp[base + e];
        int pos = atomicAdd(&lcur[val >> 16], 1);
        srcs[base + pos] = (int)(val & 0xFFFFu);
    }
}

// ---------------------------------------------------------------------------
// Prep (one launch): f32->bf16 row-major feature convert + pack both concat
// weights [Wl;Wr]^T into MFMA fragment order.
// frag[(ot*8+ks)*64 + lane][j] = B[ks*32 + (lane>>4)*8 + j][ot*16 + (lane&15)]
// ---------------------------------------------------------------------------
__global__ __launch_bounds__(256) void k_prep(const float* __restrict__ x,
                                              unsigned short* __restrict__ xb,
                                              const float* __restrict__ W1l,
                                              const float* __restrict__ W1r,
                                              const float* __restrict__ W2l,
                                              const float* __restrict__ W2r,
                                              unsigned short* __restrict__ wbuf1,
                                              unsigned short* __restrict__ wbuf2) {
    int i = blockIdx.x * 256 + threadIdx.x;
    const int n8 = N_NODES * 16;            // 800000 8-elem conversions
    if (i < n8) {
        const float4* p = (const float4*)(x + (size_t)i * 8);
        float4 a = p[0], b = p[1];
        union { unsigned short s[8]; uint4 u; } o;
        o.s[0] = f2bf(a.x); o.s[1] = f2bf(a.y); o.s[2] = f2bf(a.z); o.s[3] = f2bf(a.w);
        o.s[4] = f2bf(b.x); o.s[5] = f2bf(b.y); o.s[6] = f2bf(b.z); o.s[7] = f2bf(b.w);
        *(uint4*)(xb + (size_t)i * 8) = o.u;
        return;
    }
    int tid = i - n8;
    if (tid >= 2 * 8 * 8 * 64) return;
    int which = tid >> 12;
    int id    = tid & 4095;
    const float* Wl = which ? W2l : W1l;
    const float* Wr = which ? W2r : W1r;
    unsigned short* wbuf = which ? wbuf2 : wbuf1;
    int lane = id & 63;
    int ks   = (id >> 6) & 7;
    int ot   = id >> 9;
    int o  = ot * 16 + (lane & 15);
    int kb = ks * 32 + ((lane >> 4) << 3);
    union { unsigned short s[8]; uint4 u; } frag;
    #pragma unroll
    for (int j = 0; j < 8; ++j) {
        int k = kb + j;
        float v = (k < DIM) ? Wl[o * DIM + k] : Wr[o * DIM + (k - DIM)];
        frag.s[j] = f2bf(v);
    }
    *(uint4*)(wbuf + (size_t)id * 8) = frag.u;
}

// ---------------------------------------------------------------------------
// FUSED SAGE layer, depth-12 + lazy-B experiment (concurrency model r11-r13:
// time ~ 1/(waves x outstanding loads/lane); r12 = 6x8=48 -> 44.7us; this
// targets 5x12=60). Gather 12-edge unroll (48 data VGPRs in flight); B-frags
// loaded INSIDE the MFMA loop from hot 8KB wbuf (r13 proved codegen; its
// regression was the forced 64-VGPR bound, not lazy-B). No launch_bounds
// min-waves: let the allocator land ~90 VGPR -> 5 waves/SIMD.
// ---------------------------------------------------------------------------
__global__ __launch_bounds__(256) void k_sage(const unsigned short* __restrict__ feat,
                                              const unsigned short* __restrict__ in2b,
                                              const int2* __restrict__ rsse,
                                              const int* __restrict__ srcs,
                                              const unsigned short* __restrict__ wbuf,
                                              const float* __restrict__ bias,
                                              unsigned short* __restrict__ outb) {
    __shared__ unsigned short almp[16][136];   // row stride 272B
    int t    = threadIdx.x;
    int wave = t >> 6;
    int lane = t & 63;
    int n0   = blockIdx.x * 16;

    // ---- phase 1: gather-mean; lane (q,sub) owns node q's 16B chunk sub ----
    {
        int q   = lane >> 4;
        int sub = lane & 15;
        int node  = n0 + wave * 4 + q;
        int2 se   = rsse[node];
        int start = se.x;
        int end   = se.y;
        float a0 = 0.f, a1 = 0.f, a2 = 0.f, a3 = 0.f;
        float a4 = 0.f, a5 = 0.f, a6 = 0.f, a7 = 0.f;
        const size_t coff = (size_t)sub * 8;

#define ACC8(r) { a0 += bflo(r.x); a1 += bfhi(r.x); a2 += bflo(r.y); a3 += bfhi(r.y); \
                  a4 += bflo(r.z); a5 += bfhi(r.z); a6 += bflo(r.w); a7 += bfhi(r.w); }
        int e = start;
        for (; e + 12 <= end; e += 12) {
            int s0 = srcs[e + 0], s1 = srcs[e + 1], s2 = srcs[e + 2];
            int s3 = srcs[e + 3], s4 = srcs[e + 4], s5 = srcs[e + 5];
            int s6 = srcs[e + 6], s7 = srcs[e + 7], s8 = srcs[e + 8];
            int s9 = srcs[e + 9], s10 = srcs[e + 10], s11 = srcs[e + 11];
            uint4 r0  = *(const uint4*)(feat + (size_t)s0  * DIM + coff);
            uint4 r1  = *(const uint4*)(feat + (size_t)s1  * DIM + coff);
            uint4 r2  = *(const uint4*)(feat + (size_t)s2  * DIM + coff);
            uint4 r3  = *(const uint4*)(feat + (size_t)s3  * DIM + coff);
            uint4 r4  = *(const uint4*)(feat + (size_t)s4  * DIM + coff);
            uint4 r5  = *(const uint4*)(feat + (size_t)s5  * DIM + coff);
            uint4 r6  = *(const uint4*)(feat + (size_t)s6  * DIM + coff);
            uint4 r7  = *(const uint4*)(feat + (size_t)s7  * DIM + coff);
            uint4 r8  = *(const uint4*)(feat + (size_t)s8  * DIM + coff);
            uint4 r9  = *(const uint4*)(feat + (size_t)s9  * DIM + coff);
            uint4 r10 = *(const uint4*)(feat + (size_t)s10 * DIM + coff);
            uint4 r11 = *(const uint4*)(feat + (size_t)s11 * DIM + coff);
            ACC8(r0) ACC8(r1) ACC8(r2) ACC8(r3) ACC8(r4) ACC8(r5)
            ACC8(r6) ACC8(r7) ACC8(r8) ACC8(r9) ACC8(r10) ACC8(r11)
        }
        for (; e + 4 <= end; e += 4) {
            uint4 r0 = *(const uint4*)(feat + (size_t)srcs[e + 0] * DIM + coff);
            uint4 r1 = *(const uint4*)(feat + (size_t)srcs[e + 1] * DIM + coff);
            uint4 r2 = *(const uint4*)(feat + (size_t)srcs[e + 2] * DIM + coff);
            uint4 r3 = *(const uint4*)(feat + (size_t)srcs[e + 3] * DIM + coff);
            ACC8(r0) ACC8(r1) ACC8(r2) ACC8(r3)
        }
        for (; e < end; ++e) {
            uint4 r0 = *(const uint4*)(feat + (size_t)srcs[e] * DIM + coff);
            ACC8(r0)
        }
#undef ACC8
        float inv = 1.0f / fmaxf((float)(end - start), 1.0f);
        union { unsigned short s[8]; uint4 u; } o;
        o.s[0] = f2bf(a0 * inv); o.s[1] = f2bf(a1 * inv);
        o.s[2] = f2bf(a2 * inv); o.s[3] = f2bf(a3 * inv);
        o.s[4] = f2bf(a4 * inv); o.s[5] = f2bf(a5 * inv);
        o.s[6] = f2bf(a6 * inv); o.s[7] = f2bf(a7 * inv);
        *(uint4*)&almp[wave * 4 + q][sub * 8] = o.u;
    }
    __syncthreads();

    // ---- phase 2: MFMA (B-frags loaded per k-step from hot wbuf) ----
    int row = lane & 15;
    int kl  = (lane >> 4) << 3;
    bf16x8 A[8];
    #pragma unroll
    for (int ks = 0; ks < 4; ++ks)
        A[ks] = *(const bf16x8*)&almp[row][kl + ks * 32];
    const unsigned short* xrow = in2b + (size_t)(n0 + row) * DIM + kl;
    #pragma unroll
    for (int ks = 0; ks < 4; ++ks)
        A[4 + ks] = *(const bf16x8*)(xrow + ks * 32);

    const unsigned short* wb0 = wbuf + ((size_t)(wave * 2)     * 8 * 64 + lane) * 8;
    const unsigned short* wb1 = wbuf + ((size_t)(wave * 2 + 1) * 8 * 64 + lane) * 8;
    f32x4 acc0 = {0.f, 0.f, 0.f, 0.f}, acc1 = {0.f, 0.f, 0.f, 0.f};
    #pragma unroll
    for (int ks = 0; ks < 8; ++ks) {
        bf16x8 b0 = *(const bf16x8*)(wb0 + (size_t)ks * 64 * 8);
        bf16x8 b1 = *(const bf16x8*)(wb1 + (size_t)ks * 64 * 8);
        acc0 = __builtin_amdgcn_mfma_f32_16x16x32_bf16(A[ks], b0, acc0, 0, 0, 0);
        acc1 = __builtin_amdgcn_mfma_f32_16x16x32_bf16(A[ks], b1, acc1, 0, 0, 0);
    }

    // C/D layout: col = lane&15, row = (lane>>4)*4 + reg   [m89-verified]
    int o0   = wave * 32;
    int ocol = lane & 15;
    int rb   = (lane >> 4) << 2;
    float b0 = bias[o0 + ocol];
    float b1 = bias[o0 + 16 + ocol];
    #pragma unroll
    for (int r = 0; r < 4; ++r) {
        size_t n = (size_t)(n0 + rb + r);
        outb[n * DIM + o0 + ocol]      = f2bf(fmaxf(acc0[r] + b0, 0.f));
        outb[n * DIM + o0 + 16 + ocol] = f2bf(fmaxf(acc1[r] + b1, 0.f));
    }
}

// ---------------------------------------------------------------------------
// Pool stage 1: partial per-graph sums (batch sorted; flush on graph change).
// ---------------------------------------------------------------------------
__global__ __launch_bounds__(256) void k_pool_partial(const unsigned short* __restrict__ h2,
                                                      const int* __restrict__ batch,
                                                      float* __restrict__ gsum) {
    int wid  = (blockIdx.x * 256 + threadIdx.x) >> 6;
    int lane = threadIdx.x & 63;
    int n0 = wid * 32;
    if (n0 >= N_NODES) return;
    int n1 = n0 + 32; if (n1 > N_NODES) n1 = N_NODES;
    int col = lane * 2;

    float ax = 0.f, ay = 0.f;
    int cur = batch[n0];
    for (int n = n0; n < n1; ++n) {
        int b = batch[n];
        if (b != cur) {
            atomicAdd(&gsum[cur * DIM + col], ax);
            atomicAdd(&gsum[cur * DIM + col + 1], ay);
            ax = 0.f; ay = 0.f; cur = b;
        }
        unsigned u = *(const unsigned*)(h2 + (size_t)n * DIM + col);
        ax += bflo(u); ay += bfhi(u);
    }
    atomicAdd(&gsum[cur * DIM + col], ax);
    atomicAdd(&gsum[cur * DIM + col + 1], ay);
}

// ---------------------------------------------------------------------------
// Pool stage 2: mean + MLP head. One block per graph.
// ---------------------------------------------------------------------------
__global__ __launch_bounds__(256) void k_head(const float* __restrict__ gsum,
                                              const int* __restrict__ batch,
                                              const float* __restrict__ wl1,
                                              const float* __restrict__ bl1,
                                              const float* __restrict__ wout,
                                              const float* __restrict__ bout,
                                              float* __restrict__ out) {
    int g = blockIdx.x;
    int t = threadIdx.x;

    int lo = 0, hi = N_NODES;
    while (lo < hi) { int mid = (lo + hi) >> 1; if (batch[mid] < g) lo = mid + 1; else hi = mid; }
    int s = lo;
    lo = 0; hi = N_NODES;
    while (lo < hi) { int mid = (lo + hi) >> 1; if (batch[mid] < g + 1) lo = mid + 1; else hi = mid; }
    int e = lo;

    __shared__ float gvec[DIM];
    if (t < DIM) {
        float cnt = fmaxf((float)(e - s), 1.0f);
        gvec[t] = gsum[g * DIM + t] / cnt;
    }
    __syncthreads();
    if (t < 64) {
        float a = bl1[t];
        #pragma unroll 4
        for (int k = 0; k < DIM; ++k) a += wl1[t * DIM + k] * gvec[k];
        float g1 = fmaxf(a, 0.f) * wout[t];
        #pragma unroll
        for (int off = 32; off > 0; off >>= 1) g1 += __shfl_down(g1, off);
        if (t == 0) {
            float z = g1 + bout[0];
            out[g] = 1.0f / (1.0f + expf(-z));
        }
    }
}

// ---------------------------------------------------------------------------
extern "C" void kernel_launch(void* const* d_in, const int* in_sizes, int n_in,
                              void* d_out, int out_size, void* d_ws, size_t ws_size,
                              hipStream_t stream) {
    const float* x     = (const float*)d_in[0];
    const int*   ei    = (const int*)d_in[1];    // int64 in ref -> int32 here
    const int*   batch = (const int*)d_in[2];
    const float* w1l   = (const float*)d_in[3];
    const float* b1l   = (const float*)d_in[4];
    const float* w1r   = (const float*)d_in[5];
    const float* w2l   = (const float*)d_in[6];
    const float* b2l   = (const float*)d_in[7];
    const float* w2r   = (const float*)d_in[8];
    const float* wl1   = (const float*)d_in[9];
    const float* bl1   = (const float*)d_in[10];
    const float* wout  = (const float*)d_in[11];
    const float* bout  = (const float*)d_in[12];
    float* out = (float*)d_out;

    char*  wsp = (char*)d_ws;
    size_t off = 0;
    auto alloc = [&](size_t bytes) -> char* {
        char* p = wsp + off;
        off += (bytes + 255) & ~(size_t)255;
        return p;
    };
    int*  bcur = (int*)alloc((size_t)NB * BPAD * 4);
    int2* rsse = (int2*)alloc((size_t)N_NODES * 8);
    int*  srcs = (int*)alloc((size_t)NB * CAP * 4);
    unsigned* tmp = (unsigned*)alloc((size_t)NB * CAP * 4);
    unsigned short* xb    = (unsigned short*)alloc((size_t)N_NODES * DIM * 2);
    unsigned short* h1b   = (unsigned short*)alloc((size_t)N_NODES * DIM * 2);
    unsigned short* h2b   = (unsigned short*)alloc((size_t)N_NODES * DIM * 2);
    unsigned short* wbuf1 = (unsigned short*)alloc((size_t)8 * 8 * 64 * 8 * 2);
    unsigned short* wbuf2 = (unsigned short*)alloc((size_t)8 * 8 * 64 * 8 * 2);
    float* gsum = (float*)alloc((size_t)N_GRAPHS * DIM * 4);

    hipMemsetAsync(bcur, 0, (size_t)NB * BPAD * 4, stream);
    hipMemsetAsync(gsum, 0, (size_t)N_GRAPHS * DIM * 4, stream);

    // edge bucketing -> local CSR (no global hist/scan chain)
    k_bucket<<<(N_EDGES + EPB - 1) / EPB, 512, 0, stream>>>(ei, bcur, tmp);
    k_csr<<<NB, 512, 0, stream>>>(tmp, bcur, rsse, srcs);

    // dtype prep (single launch: feature convert + both weight packs)
    k_prep<<<(N_NODES * 16 + 2 * 8 * 8 * 64 + 255) / 256, 256, 0, stream>>>(
        x, xb, w1l, w1r, w2l, w2r, wbuf1, wbuf2);

    // conv1 (fused aggregate + GEMM)
    k_sage<<<N_NODES / 16, 256, 0, stream>>>(xb, xb, rsse, srcs, wbuf1, b1l, h1b);
    // conv2
    k_sage<<<N_NODES / 16, 256, 0, stream>>>(h1b, h1b, rsse, srcs, wbuf2, b2l, h2b);
    // pool (2-stage) + head
    k_pool_partial<<<(N_NODES + 127) / 128, 256, 0, stream>>>(h2b, batch, gsum);
    k_head<<<N_GRAPHS, 256, 0, stream>>>(gsum, batch, wl1, bl1, wout, bout, out);
}

// Round 16
// 149.439 us; speedup vs baseline: 1.6813x; 1.0552x over previous
//
#include <hip/hip_runtime.h>
#include <cstdint>
#include <cstddef>

#define N_NODES  50000
#define N_EDGES  800000
#define DIM      128
#define N_GRAPHS 64
#define NB       196       // coarse buckets of 256 nodes
#define BSH      8
#define EPB      2048      // edges per k_bucket block
#define BPAD     16        // bcur padding: one counter per 64B line
#define CAP      8192      // per-bucket region capacity (mean 4096, +6sigma ~4.5K)
#define NBB      391       // bucket blocks = ceil(N_EDGES/EPB)
#define NPREP    1579      // prep blocks = ceil((N_NODES*16 + 8192)/512)

typedef __attribute__((ext_vector_type(8))) short     bf16x8;
typedef __attribute__((ext_vector_type(4))) float     f32x4;

__device__ __forceinline__ int clamp_node(int v) {
    return v < 0 ? 0 : (v >= N_NODES ? N_NODES - 1 : v);
}
__device__ __forceinline__ unsigned short f2bf(float f) {
    union { float f; unsigned u; } v; v.f = f;
    unsigned r = v.u + 0x7FFF + ((v.u >> 16) & 1);   // round-to-nearest-even
    return (unsigned short)(r >> 16);
}
__device__ __forceinline__ float bflo(unsigned u) {
    union { unsigned u; float f; } v; v.u = u << 16; return v.f;
}
__device__ __forceinline__ float bfhi(unsigned u) {
    union { unsigned u; float f; } v; v.u = u & 0xFFFF0000u; return v.f;
}

// ---------------------------------------------------------------------------
// Front kernel — two block roles (block-granular divergence, r16 fusion):
//  blocks [0,NBB):        LDS counting sort of 2048 edges into 196 coarse
//                         buckets; bulk-append runs into fixed per-bucket
//                         regions tmp[b*CAP..] (bcur line-padded, staggered
//                         flush — r7 cursor-convoy lesson).
//  blocks [NBB,NBB+NPREP): f32->bf16 feature convert + MFMA-order weight
//                         packs (streams concurrently with bucket tail).
// Packed entry: src (16b) | dst_local (8b) << 16.
// ---------------------------------------------------------------------------
__global__ __launch_bounds__(512) void k_front(const int* __restrict__ ei,
                                               int* __restrict__ bcur,
                                               unsigned* __restrict__ tmp,
                                               const float* __restrict__ x,
                                               unsigned short* __restrict__ xb,
                                               const float* __restrict__ W1l,
                                               const float* __restrict__ W1r,
                                               const float* __restrict__ W2l,
                                               const float* __restrict__ W2r,
                                               unsigned short* __restrict__ wbuf1,
                                               unsigned short* __restrict__ wbuf2) {
    int t = threadIdx.x;

    if (blockIdx.x >= NBB) {
        // ---------------- prep role ----------------
        int i = (blockIdx.x - NBB) * 512 + t;
        const int n8 = N_NODES * 16;            // 800000 8-elem conversions
        if (i < n8) {
            const float4* p = (const float4*)(x + (size_t)i * 8);
            float4 a = p[0], b = p[1];
            union { unsigned short s[8]; uint4 u; } o;
            o.s[0] = f2bf(a.x); o.s[1] = f2bf(a.y); o.s[2] = f2bf(a.z); o.s[3] = f2bf(a.w);
            o.s[4] = f2bf(b.x); o.s[5] = f2bf(b.y); o.s[6] = f2bf(b.z); o.s[7] = f2bf(b.w);
            *(uint4*)(xb + (size_t)i * 8) = o.u;
            return;
        }
        int tid = i - n8;
        if (tid >= 2 * 8 * 8 * 64) return;
        int which = tid >> 12;
        int id    = tid & 4095;
        const float* Wl = which ? W2l : W1l;
        const float* Wr = which ? W2r : W1r;
        unsigned short* wbuf = which ? wbuf2 : wbuf1;
        int lane = id & 63;
        int ks   = (id >> 6) & 7;
        int ot   = id >> 9;
        int o  = ot * 16 + (lane & 15);
        int kb = ks * 32 + ((lane >> 4) << 3);
        union { unsigned short s[8]; uint4 u; } frag;
        #pragma unroll
        for (int j = 0; j < 8; ++j) {
            int k = kb + j;
            float v = (k < DIM) ? Wl[o * DIM + k] : Wr[o * DIM + (k - DIM)];
            frag.s[j] = f2bf(v);
        }
        *(uint4*)(wbuf + (size_t)id * 8) = frag.u;
        return;
    }

    // ---------------- bucket role ----------------
    __shared__ int cnt[256], cur[256], ofs[256];
    __shared__ int s[512];
    __shared__ unsigned list[EPB];
    int base = blockIdx.x * EPB;
    int eend = base + EPB; if (eend > N_EDGES) eend = N_EDGES;

    if (t < 256) cnt[t] = 0;
    __syncthreads();

    int d[4], sv[4];
    bool ok[4];
    #pragma unroll
    for (int i = 0; i < 4; ++i) {
        int e = base + t + i * 512;
        ok[i] = (e < eend);
        if (ok[i]) {
            d[i]  = clamp_node(ei[N_EDGES + e]);
            sv[i] = clamp_node(ei[e]);
            atomicAdd(&cnt[d[i] >> BSH], 1);
        }
    }
    __syncthreads();
    int v = (t < 256) ? cnt[t] : 0;
    s[t] = v;
    __syncthreads();
    for (int off = 1; off < 256; off <<= 1) {
        int y = (t >= off && t < 256) ? s[t - off] : 0;
        __syncthreads();
        if (t < 256) s[t] += y;
        __syncthreads();
    }
    if (t < 256) { ofs[t] = s[t] - v; cur[t] = s[t] - v; }
    __syncthreads();
    #pragma unroll
    for (int i = 0; i < 4; ++i) {
        if (ok[i]) {
            int b = d[i] >> BSH;
            int p = atomicAdd(&cur[b], 1);
            list[p] = (unsigned)sv[i] | ((unsigned)(d[i] & 255) << 16);
        }
    }
    __syncthreads();
    int wv = t >> 6, lane = t & 63;
    const int NGRP = 25;   // ceil(196/8)
    for (int jj = 0; jj < NGRP; ++jj) {
        int b = wv + 8 * ((jj + (int)blockIdx.x) % NGRP);
        if (b >= NB) continue;
        int c = cnt[b];
        if (c == 0) continue;
        int gpos;
        if (lane == 0) gpos = atomicAdd(&bcur[b * BPAD], c);
        gpos = __shfl(gpos, 0);
        if (gpos + c > CAP) c = (gpos < CAP) ? (CAP - gpos) : 0;  // defensive
        int ls = ofs[b];
        for (int i = lane; i < c; i += 64) tmp[b * CAP + gpos + i] = list[ls + i];
    }
}

// ---------------------------------------------------------------------------
// Local CSR build: one block per bucket. LDS 256-node histogram over the
// bucket run -> scan -> per-node {start,end} (rsse, int2) -> scatter srcs
// into node order within the bucket's exclusive region. Also zeroes gsum
// (replaces a memset dispatch).
// ---------------------------------------------------------------------------
__global__ __launch_bounds__(512) void k_csr(const unsigned* __restrict__ tmp,
                                             const int* __restrict__ bcur,
                                             int2* __restrict__ rsse,
                                             int* __restrict__ srcs,
                                             float* __restrict__ gsum) {
    __shared__ int lh[256], lcur[256];
    __shared__ int s[512];
    int b = blockIdx.x;
    int t = threadIdx.x;
    int base = b * CAP;
    int nc = bcur[b * BPAD];
    if (nc > CAP) nc = CAP;

    int gi = b * 512 + t;
    if (gi < N_GRAPHS * DIM) gsum[gi] = 0.f;

    if (t < 256) lh[t] = 0;
    __syncthreads();
    for (int e = t; e < nc; e += 512)
        atomicAdd(&lh[tmp[base + e] >> 16], 1);
    __syncthreads();
    int v = (t < 256) ? lh[t] : 0;
    s[t] = v;
    __syncthreads();
    for (int off = 1; off < 256; off <<= 1) {
        int y = (t >= off && t < 256) ? s[t - off] : 0;
        __syncthreads();
        if (t < 256) s[t] += y;
        __syncthreads();
    }
    if (t < 256) {
        int st = s[t] - v;                 // exclusive local start
        lcur[t] = st;
        int node = (b << BSH) + t;
        if (node < N_NODES) rsse[node] = make_int2(base + st, base + st + v);
    }
    __syncthreads();
    for (int e = t; e < nc; e += 512) {
        unsigned val = tmp[base + e];
        int pos = atomicAdd(&lcur[val >> 16], 1);
        srcs[base + pos] = (int)(val & 0xFFFFu);
    }
}

// ---------------------------------------------------------------------------
// FUSED SAGE layer — FROZEN r15 form (43.6us, VGPR 64, occupancy 31%; the
// gather is at the random-line service-rate roofline: concurrency 32/48/60,
// VGPR 32-88, and two L2-locality restructures all land 43.6-61us with
// 43.6 the floor). Gather 12-edge unroll; B-frags loaded inside the MFMA
// loop from the hot 8KB wbuf; root A-frags after the barrier.
// ---------------------------------------------------------------------------
__global__ __launch_bounds__(256) void k_sage(const unsigned short* __restrict__ feat,
                                              const unsigned short* __restrict__ in2b,
                                              const int2* __restrict__ rsse,
                                              const int* __restrict__ srcs,
                                              const unsigned short* __restrict__ wbuf,
                                              const float* __restrict__ bias,
                                              unsigned short* __restrict__ outb) {
    __shared__ unsigned short almp[16][136];   // row stride 272B
    int t    = threadIdx.x;
    int wave = t >> 6;
    int lane = t & 63;
    int n0   = blockIdx.x * 16;

    // ---- phase 1: gather-mean; lane (q,sub) owns node q's 16B chunk sub ----
    {
        int q   = lane >> 4;
        int sub = lane & 15;
        int node  = n0 + wave * 4 + q;
        int2 se   = rsse[node];
        int start = se.x;
        int end   = se.y;
        float a0 = 0.f, a1 = 0.f, a2 = 0.f, a3 = 0.f;
        float a4 = 0.f, a5 = 0.f, a6 = 0.f, a7 = 0.f;
        const size_t coff = (size_t)sub * 8;

#define ACC8(r) { a0 += bflo(r.x); a1 += bfhi(r.x); a2 += bflo(r.y); a3 += bfhi(r.y); \
                  a4 += bflo(r.z); a5 += bfhi(r.z); a6 += bflo(r.w); a7 += bfhi(r.w); }
        int e = start;
        for (; e + 12 <= end; e += 12) {
            int s0 = srcs[e + 0], s1 = srcs[e + 1], s2 = srcs[e + 2];
            int s3 = srcs[e + 3], s4 = srcs[e + 4], s5 = srcs[e + 5];
            int s6 = srcs[e + 6], s7 = srcs[e + 7], s8 = srcs[e + 8];
            int s9 = srcs[e + 9], s10 = srcs[e + 10], s11 = srcs[e + 11];
            uint4 r0  = *(const uint4*)(feat + (size_t)s0  * DIM + coff);
            uint4 r1  = *(const uint4*)(feat + (size_t)s1  * DIM + coff);
            uint4 r2  = *(const uint4*)(feat + (size_t)s2  * DIM + coff);
            uint4 r3  = *(const uint4*)(feat + (size_t)s3  * DIM + coff);
            uint4 r4  = *(const uint4*)(feat + (size_t)s4  * DIM + coff);
            uint4 r5  = *(const uint4*)(feat + (size_t)s5  * DIM + coff);
            uint4 r6  = *(const uint4*)(feat + (size_t)s6  * DIM + coff);
            uint4 r7  = *(const uint4*)(feat + (size_t)s7  * DIM + coff);
            uint4 r8  = *(const uint4*)(feat + (size_t)s8  * DIM + coff);
            uint4 r9  = *(const uint4*)(feat + (size_t)s9  * DIM + coff);
            uint4 r10 = *(const uint4*)(feat + (size_t)s10 * DIM + coff);
            uint4 r11 = *(const uint4*)(feat + (size_t)s11 * DIM + coff);
            ACC8(r0) ACC8(r1) ACC8(r2) ACC8(r3) ACC8(r4) ACC8(r5)
            ACC8(r6) ACC8(r7) ACC8(r8) ACC8(r9) ACC8(r10) ACC8(r11)
        }
        for (; e + 4 <= end; e += 4) {
            uint4 r0 = *(const uint4*)(feat + (size_t)srcs[e + 0] * DIM + coff);
            uint4 r1 = *(const uint4*)(feat + (size_t)srcs[e + 1] * DIM + coff);
            uint4 r2 = *(const uint4*)(feat + (size_t)srcs[e + 2] * DIM + coff);
            uint4 r3 = *(const uint4*)(feat + (size_t)srcs[e + 3] * DIM + coff);
            ACC8(r0) ACC8(r1) ACC8(r2) ACC8(r3)
        }
        for (; e < end; ++e) {
            uint4 r0 = *(const uint4*)(feat + (size_t)srcs[e] * DIM + coff);
            ACC8(r0)
        }
#undef ACC8
        float inv = 1.0f / fmaxf((float)(end - start), 1.0f);
        union { unsigned short s[8]; uint4 u; } o;
        o.s[0] = f2bf(a0 * inv); o.s[1] = f2bf(a1 * inv);
        o.s[2] = f2bf(a2 * inv); o.s[3] = f2bf(a3 * inv);
        o.s[4] = f2bf(a4 * inv); o.s[5] = f2bf(a5 * inv);
        o.s[6] = f2bf(a6 * inv); o.s[7] = f2bf(a7 * inv);
        *(uint4*)&almp[wave * 4 + q][sub * 8] = o.u;
    }
    __syncthreads();

    // ---- phase 2: MFMA (B-frags loaded per k-step from hot wbuf) ----
    int row = lane & 15;
    int kl  = (lane >> 4) << 3;
    bf16x8 A[8];
    #pragma unroll
    for (int ks = 0; ks < 4; ++ks)
        A[ks] = *(const bf16x8*)&almp[row][kl + ks * 32];
    const unsigned short* xrow = in2b + (size_t)(n0 + row) * DIM + kl;
    #pragma unroll
    for (int ks = 0; ks < 4; ++ks)
        A[4 + ks] = *(const bf16x8*)(xrow + ks * 32);

    const unsigned short* wb0 = wbuf + ((size_t)(wave * 2)     * 8 * 64 + lane) * 8;
    const unsigned short* wb1 = wbuf + ((size_t)(wave * 2 + 1) * 8 * 64 + lane) * 8;
    f32x4 acc0 = {0.f, 0.f, 0.f, 0.f}, acc1 = {0.f, 0.f, 0.f, 0.f};
    #pragma unroll
    for (int ks = 0; ks < 8; ++ks) {
        bf16x8 b0 = *(const bf16x8*)(wb0 + (size_t)ks * 64 * 8);
        bf16x8 b1 = *(const bf16x8*)(wb1 + (size_t)ks * 64 * 8);
        acc0 = __builtin_amdgcn_mfma_f32_16x16x32_bf16(A[ks], b0, acc0, 0, 0, 0);
        acc1 = __builtin_amdgcn_mfma_f32_16x16x32_bf16(A[ks], b1, acc1, 0, 0, 0);
    }

    // C/D layout: col = lane&15, row = (lane>>4)*4 + reg   [m89-verified]
    int o0   = wave * 32;
    int ocol = lane & 15;
    int rb   = (lane >> 4) << 2;
    float b0 = bias[o0 + ocol];
    float b1 = bias[o0 + 16 + ocol];
    #pragma unroll
    for (int r = 0; r < 4; ++r) {
        size_t n = (size_t)(n0 + rb + r);
        outb[n * DIM + o0 + ocol]      = f2bf(fmaxf(acc0[r] + b0, 0.f));
        outb[n * DIM + o0 + 16 + ocol] = f2bf(fmaxf(acc1[r] + b1, 0.f));
    }
}

// ---------------------------------------------------------------------------
// Pool stage 1: partial per-graph sums (batch sorted; flush on graph change).
// ---------------------------------------------------------------------------
__global__ __launch_bounds__(256) void k_pool_partial(const unsigned short* __restrict__ h2,
                                                      const int* __restrict__ batch,
                                                      float* __restrict__ gsum) {
    int wid  = (blockIdx.x * 256 + threadIdx.x) >> 6;
    int lane = threadIdx.x & 63;
    int n0 = wid * 32;
    if (n0 >= N_NODES) return;
    int n1 = n0 + 32; if (n1 > N_NODES) n1 = N_NODES;
    int col = lane * 2;

    float ax = 0.f, ay = 0.f;
    int cur = batch[n0];
    for (int n = n0; n < n1; ++n) {
        int b = batch[n];
        if (b != cur) {
            atomicAdd(&gsum[cur * DIM + col], ax);
            atomicAdd(&gsum[cur * DIM + col + 1], ay);
            ax = 0.f; ay = 0.f; cur = b;
        }
        unsigned u = *(const unsigned*)(h2 + (size_t)n * DIM + col);
        ax += bflo(u); ay += bfhi(u);
    }
    atomicAdd(&gsum[cur * DIM + col], ax);
    atomicAdd(&gsum[cur * DIM + col + 1], ay);
}

// ---------------------------------------------------------------------------
// Pool stage 2: mean + MLP head. One block per graph.
// ---------------------------------------------------------------------------
__global__ __launch_bounds__(256) void k_head(const float* __restrict__ gsum,
                                              const int* __restrict__ batch,
                                              const float* __restrict__ wl1,
                                              const float* __restrict__ bl1,
                                              const float* __restrict__ wout,
                                              const float* __restrict__ bout,
                                              float* __restrict__ out) {
    int g = blockIdx.x;
    int t = threadIdx.x;

    int lo = 0, hi = N_NODES;
    while (lo < hi) { int mid = (lo + hi) >> 1; if (batch[mid] < g) lo = mid + 1; else hi = mid; }
    int s = lo;
    lo = 0; hi = N_NODES;
    while (lo < hi) { int mid = (lo + hi) >> 1; if (batch[mid] < g + 1) lo = mid + 1; else hi = mid; }
    int e = lo;

    __shared__ float gvec[DIM];
    if (t < DIM) {
        float cnt = fmaxf((float)(e - s), 1.0f);
        gvec[t] = gsum[g * DIM + t] / cnt;
    }
    __syncthreads();
    if (t < 64) {
        float a = bl1[t];
        #pragma unroll 4
        for (int k = 0; k < DIM; ++k) a += wl1[t * DIM + k] * gvec[k];
        float g1 = fmaxf(a, 0.f) * wout[t];
        #pragma unroll
        for (int off = 32; off > 0; off >>= 1) g1 += __shfl_down(g1, off);
        if (t == 0) {
            float z = g1 + bout[0];
            out[g] = 1.0f / (1.0f + expf(-z));
        }
    }
}

// ---------------------------------------------------------------------------
extern "C" void kernel_launch(void* const* d_in, const int* in_sizes, int n_in,
                              void* d_out, int out_size, void* d_ws, size_t ws_size,
                              hipStream_t stream) {
    const float* x     = (const float*)d_in[0];
    const int*   ei    = (const int*)d_in[1];    // int64 in ref -> int32 here
    const int*   batch = (const int*)d_in[2];
    const float* w1l   = (const float*)d_in[3];
    const float* b1l   = (const float*)d_in[4];
    const float* w1r   = (const float*)d_in[5];
    const float* w2l   = (const float*)d_in[6];
    const float* b2l   = (const float*)d_in[7];
    const float* w2r   = (const float*)d_in[8];
    const float* wl1   = (const float*)d_in[9];
    const float* bl1   = (const float*)d_in[10];
    const float* wout  = (const float*)d_in[11];
    const float* bout  = (const float*)d_in[12];
    float* out = (float*)d_out;

    char*  wsp = (char*)d_ws;
    size_t off = 0;
    auto alloc = [&](size_t bytes) -> char* {
        char* p = wsp + off;
        off += (bytes + 255) & ~(size_t)255;
        return p;
    };
    int*  bcur = (int*)alloc((size_t)NB * BPAD * 4);
    int2* rsse = (int2*)alloc((size_t)N_NODES * 8);
    int*  srcs = (int*)alloc((size_t)NB * CAP * 4);
    unsigned* tmp = (unsigned*)alloc((size_t)NB * CAP * 4);
    unsigned short* xb    = (unsigned short*)alloc((size_t)N_NODES * DIM * 2);
    unsigned short* h1b   = (unsigned short*)alloc((size_t)N_NODES * DIM * 2);
    unsigned short* h2b   = (unsigned short*)alloc((size_t)N_NODES * DIM * 2);
    unsigned short* wbuf1 = (unsigned short*)alloc((size_t)8 * 8 * 64 * 8 * 2);
    unsigned short* wbuf2 = (unsigned short*)alloc((size_t)8 * 8 * 64 * 8 * 2);
    float* gsum = (float*)alloc((size_t)N_GRAPHS * DIM * 4);

    hipMemsetAsync(bcur, 0, (size_t)NB * BPAD * 4, stream);

    // fused front: edge bucketing || (bf16 convert + weight packs)
    k_front<<<NBB + NPREP, 512, 0, stream>>>(ei, bcur, tmp, x, xb,
                                             w1l, w1r, w2l, w2r, wbuf1, wbuf2);
    // local CSR (+ gsum zeroing)
    k_csr<<<NB, 512, 0, stream>>>(tmp, bcur, rsse, srcs, gsum);

    // conv1 (fused aggregate + GEMM)
    k_sage<<<N_NODES / 16, 256, 0, stream>>>(xb, xb, rsse, srcs, wbuf1, b1l, h1b);
    // conv2
    k_sage<<<N_NODES / 16, 256, 0, stream>>>(h1b, h1b, rsse, srcs, wbuf2, b2l, h2b);
    // pool (2-stage) + head
    k_pool_partial<<<(N_NODES + 127) / 128, 256, 0, stream>>>(h2b, batch, gsum);
    k_head<<<N_GRAPHS, 256, 0, stream>>>(gsum, batch, wl1, bl1, wout, bout, out);
}

// Round 17
// 135.060 us; speedup vs baseline: 1.8603x; 1.1065x over previous
//
#include <hip/hip_runtime.h>
#include <cstdint>
#include <cstddef>

#define N_NODES  50000
#define N_EDGES  800000
#define DIM      128
#define N_GRAPHS 64
#define NB       196       // coarse buckets of 256 nodes
#define BSH      8
#define EPB      2048      // edges per k_bucket block
#define BPAD     16        // bcur padding: one counter per 64B line
#define CAP      8192      // per-bucket region capacity (mean 4096, +6sigma ~4.5K)
#define NBB      391       // bucket blocks = ceil(N_EDGES/EPB)
#define NPREP    1579      // prep blocks = ceil((N_NODES*16 + 8192)/512)

typedef __attribute__((ext_vector_type(8))) short     bf16x8;
typedef __attribute__((ext_vector_type(4))) float     f32x4;

__device__ __forceinline__ int clamp_node(int v) {
    return v < 0 ? 0 : (v >= N_NODES ? N_NODES - 1 : v);
}
__device__ __forceinline__ unsigned short f2bf(float f) {
    union { float f; unsigned u; } v; v.f = f;
    unsigned r = v.u + 0x7FFF + ((v.u >> 16) & 1);   // round-to-nearest-even
    return (unsigned short)(r >> 16);
}
__device__ __forceinline__ float bflo(unsigned u) {
    union { unsigned u; float f; } v; v.u = u << 16; return v.f;
}
__device__ __forceinline__ float bfhi(unsigned u) {
    union { unsigned u; float f; } v; v.u = u & 0xFFFF0000u; return v.f;
}

// ---------------------------------------------------------------------------
// Front kernel — two block roles (block-granular divergence):
//  blocks [0,NBB):        LDS counting sort of 2048 edges into 196 coarse
//                         buckets; bulk-append runs into fixed per-bucket
//                         regions tmp[b*CAP..] (bcur line-padded, staggered
//                         flush — r7 cursor-convoy lesson).
//  blocks [NBB,NBB+NPREP): f32->bf16 feature convert + MFMA-order weight
//                         packs (streams concurrently with bucket tail).
// Packed entry: src (16b) | dst_local (8b) << 16.
// ---------------------------------------------------------------------------
__global__ __launch_bounds__(512) void k_front(const int* __restrict__ ei,
                                               int* __restrict__ bcur,
                                               unsigned* __restrict__ tmp,
                                               const float* __restrict__ x,
                                               unsigned short* __restrict__ xb,
                                               const float* __restrict__ W1l,
                                               const float* __restrict__ W1r,
                                               const float* __restrict__ W2l,
                                               const float* __restrict__ W2r,
                                               unsigned short* __restrict__ wbuf1,
                                               unsigned short* __restrict__ wbuf2) {
    int t = threadIdx.x;

    if (blockIdx.x >= NBB) {
        // ---------------- prep role ----------------
        int i = (blockIdx.x - NBB) * 512 + t;
        const int n8 = N_NODES * 16;            // 800000 8-elem conversions
        if (i < n8) {
            const float4* p = (const float4*)(x + (size_t)i * 8);
            float4 a = p[0], b = p[1];
            union { unsigned short s[8]; uint4 u; } o;
            o.s[0] = f2bf(a.x); o.s[1] = f2bf(a.y); o.s[2] = f2bf(a.z); o.s[3] = f2bf(a.w);
            o.s[4] = f2bf(b.x); o.s[5] = f2bf(b.y); o.s[6] = f2bf(b.z); o.s[7] = f2bf(b.w);
            *(uint4*)(xb + (size_t)i * 8) = o.u;
            return;
        }
        int tid = i - n8;
        if (tid >= 2 * 8 * 8 * 64) return;
        int which = tid >> 12;
        int id    = tid & 4095;
        const float* Wl = which ? W2l : W1l;
        const float* Wr = which ? W2r : W1r;
        unsigned short* wbuf = which ? wbuf2 : wbuf1;
        int lane = id & 63;
        int ks   = (id >> 6) & 7;
        int ot   = id >> 9;
        int o  = ot * 16 + (lane & 15);
        int kb = ks * 32 + ((lane >> 4) << 3);
        union { unsigned short s[8]; uint4 u; } frag;
        #pragma unroll
        for (int j = 0; j < 8; ++j) {
            int k = kb + j;
            float v = (k < DIM) ? Wl[o * DIM + k] : Wr[o * DIM + (k - DIM)];
            frag.s[j] = f2bf(v);
        }
        *(uint4*)(wbuf + (size_t)id * 8) = frag.u;
        return;
    }

    // ---------------- bucket role ----------------
    __shared__ int cnt[256], cur[256], ofs[256];
    __shared__ int s[512];
    __shared__ unsigned list[EPB];
    int base = blockIdx.x * EPB;
    int eend = base + EPB; if (eend > N_EDGES) eend = N_EDGES;

    if (t < 256) cnt[t] = 0;
    __syncthreads();

    int d[4], sv[4];
    bool ok[4];
    #pragma unroll
    for (int i = 0; i < 4; ++i) {
        int e = base + t + i * 512;
        ok[i] = (e < eend);
        if (ok[i]) {
            d[i]  = clamp_node(ei[N_EDGES + e]);
            sv[i] = clamp_node(ei[e]);
            atomicAdd(&cnt[d[i] >> BSH], 1);
        }
    }
    __syncthreads();
    int v = (t < 256) ? cnt[t] : 0;
    s[t] = v;
    __syncthreads();
    for (int off = 1; off < 256; off <<= 1) {
        int y = (t >= off && t < 256) ? s[t - off] : 0;
        __syncthreads();
        if (t < 256) s[t] += y;
        __syncthreads();
    }
    if (t < 256) { ofs[t] = s[t] - v; cur[t] = s[t] - v; }
    __syncthreads();
    #pragma unroll
    for (int i = 0; i < 4; ++i) {
        if (ok[i]) {
            int b = d[i] >> BSH;
            int p = atomicAdd(&cur[b], 1);
            list[p] = (unsigned)sv[i] | ((unsigned)(d[i] & 255) << 16);
        }
    }
    __syncthreads();
    int wv = t >> 6, lane = t & 63;
    const int NGRP = 25;   // ceil(196/8)
    for (int jj = 0; jj < NGRP; ++jj) {
        int b = wv + 8 * ((jj + (int)blockIdx.x) % NGRP);
        if (b >= NB) continue;
        int c = cnt[b];
        if (c == 0) continue;
        int gpos;
        if (lane == 0) gpos = atomicAdd(&bcur[b * BPAD], c);
        gpos = __shfl(gpos, 0);
        if (gpos + c > CAP) c = (gpos < CAP) ? (CAP - gpos) : 0;  // defensive
        int ls = ofs[b];
        for (int i = lane; i < c; i += 64) tmp[b * CAP + gpos + i] = list[ls + i];
    }
}

// ---------------------------------------------------------------------------
// Local CSR build: one block per bucket. LDS 256-node histogram over the
// bucket run -> scan -> per-node {start,end} (rsse, int2) -> scatter srcs
// into node order within the bucket's exclusive region. Also zeroes gsum.
// ---------------------------------------------------------------------------
__global__ __launch_bounds__(512) void k_csr(const unsigned* __restrict__ tmp,
                                             const int* __restrict__ bcur,
                                             int2* __restrict__ rsse,
                                             int* __restrict__ srcs,
                                             float* __restrict__ gsum) {
    __shared__ int lh[256], lcur[256];
    __shared__ int s[512];
    int b = blockIdx.x;
    int t = threadIdx.x;
    int base = b * CAP;
    int nc = bcur[b * BPAD];
    if (nc > CAP) nc = CAP;

    int gi = b * 512 + t;
    if (gi < N_GRAPHS * DIM) gsum[gi] = 0.f;

    if (t < 256) lh[t] = 0;
    __syncthreads();
    for (int e = t; e < nc; e += 512)
        atomicAdd(&lh[tmp[base + e] >> 16], 1);
    __syncthreads();
    int v = (t < 256) ? lh[t] : 0;
    s[t] = v;
    __syncthreads();
    for (int off = 1; off < 256; off <<= 1) {
        int y = (t >= off && t < 256) ? s[t - off] : 0;
        __syncthreads();
        if (t < 256) s[t] += y;
        __syncthreads();
    }
    if (t < 256) {
        int st = s[t] - v;                 // exclusive local start
        lcur[t] = st;
        int node = (b << BSH) + t;
        if (node < N_NODES) rsse[node] = make_int2(base + st, base + st + v);
    }
    __syncthreads();
    for (int e = t; e < nc; e += 512) {
        unsigned val = tmp[base + e];
        int pos = atomicAdd(&lcur[val >> 16], 1);
        srcs[base + pos] = (int)(val & 0xFFFFu);
    }
}

// ---------------------------------------------------------------------------
// FUSED SAGE layer — FROZEN r15 gather/MFMA core (43.6us, VGPR 64; the gather
// is at the random-line service-rate roofline — concurrency 32/48/60, VGPR
// 32-88, two L2 restructures all ≥43.6us). Gather 12-edge unroll; B-frags
// inside the MFMA loop from hot 8KB wbuf; root A-frags after the barrier.
// POOL=1 (conv2): instead of writing h2b, fold global_mean_pool stage 1 into
// the epilogue — fast path (block's 16 nodes in one graph, ~98%: graphs avg
// 781 nodes) reduces rows in-thread + 2x shfl_xor across row-quads -> 128
// atomicAdds/block into gsum (400K total / 8192 addrs, no contention).
// Pools pre-bf16-round f32 (closer to the f32 reference than bf16 round-trip).
// ---------------------------------------------------------------------------
template<int POOL>
__global__ __launch_bounds__(256) void k_sage(const unsigned short* __restrict__ feat,
                                              const unsigned short* __restrict__ in2b,
                                              const int2* __restrict__ rsse,
                                              const int* __restrict__ srcs,
                                              const unsigned short* __restrict__ wbuf,
                                              const float* __restrict__ bias,
                                              unsigned short* __restrict__ outb,
                                              const int* __restrict__ batch,
                                              float* __restrict__ gsum) {
    __shared__ unsigned short almp[16][136];   // row stride 272B
    __shared__ int sb[16];
    int t    = threadIdx.x;
    int wave = t >> 6;
    int lane = t & 63;
    int n0   = blockIdx.x * 16;

    if (POOL && t < 16) sb[t] = batch[n0 + t];

    // ---- phase 1: gather-mean; lane (q,sub) owns node q's 16B chunk sub ----
    {
        int q   = lane >> 4;
        int sub = lane & 15;
        int node  = n0 + wave * 4 + q;
        int2 se   = rsse[node];
        int start = se.x;
        int end   = se.y;
        float a0 = 0.f, a1 = 0.f, a2 = 0.f, a3 = 0.f;
        float a4 = 0.f, a5 = 0.f, a6 = 0.f, a7 = 0.f;
        const size_t coff = (size_t)sub * 8;

#define ACC8(r) { a0 += bflo(r.x); a1 += bfhi(r.x); a2 += bflo(r.y); a3 += bfhi(r.y); \
                  a4 += bflo(r.z); a5 += bfhi(r.z); a6 += bflo(r.w); a7 += bfhi(r.w); }
        int e = start;
        for (; e + 12 <= end; e += 12) {
            int s0 = srcs[e + 0], s1 = srcs[e + 1], s2 = srcs[e + 2];
            int s3 = srcs[e + 3], s4 = srcs[e + 4], s5 = srcs[e + 5];
            int s6 = srcs[e + 6], s7 = srcs[e + 7], s8 = srcs[e + 8];
            int s9 = srcs[e + 9], s10 = srcs[e + 10], s11 = srcs[e + 11];
            uint4 r0  = *(const uint4*)(feat + (size_t)s0  * DIM + coff);
            uint4 r1  = *(const uint4*)(feat + (size_t)s1  * DIM + coff);
            uint4 r2  = *(const uint4*)(feat + (size_t)s2  * DIM + coff);
            uint4 r3  = *(const uint4*)(feat + (size_t)s3  * DIM + coff);
            uint4 r4  = *(const uint4*)(feat + (size_t)s4  * DIM + coff);
            uint4 r5  = *(const uint4*)(feat + (size_t)s5  * DIM + coff);
            uint4 r6  = *(const uint4*)(feat + (size_t)s6  * DIM + coff);
            uint4 r7  = *(const uint4*)(feat + (size_t)s7  * DIM + coff);
            uint4 r8  = *(const uint4*)(feat + (size_t)s8  * DIM + coff);
            uint4 r9  = *(const uint4*)(feat + (size_t)s9  * DIM + coff);
            uint4 r10 = *(const uint4*)(feat + (size_t)s10 * DIM + coff);
            uint4 r11 = *(const uint4*)(feat + (size_t)s11 * DIM + coff);
            ACC8(r0) ACC8(r1) ACC8(r2) ACC8(r3) ACC8(r4) ACC8(r5)
            ACC8(r6) ACC8(r7) ACC8(r8) ACC8(r9) ACC8(r10) ACC8(r11)
        }
        for (; e + 4 <= end; e += 4) {
            uint4 r0 = *(const uint4*)(feat + (size_t)srcs[e + 0] * DIM + coff);
            uint4 r1 = *(const uint4*)(feat + (size_t)srcs[e + 1] * DIM + coff);
            uint4 r2 = *(const uint4*)(feat + (size_t)srcs[e + 2] * DIM + coff);
            uint4 r3 = *(const uint4*)(feat + (size_t)srcs[e + 3] * DIM + coff);
            ACC8(r0) ACC8(r1) ACC8(r2) ACC8(r3)
        }
        for (; e < end; ++e) {
            uint4 r0 = *(const uint4*)(feat + (size_t)srcs[e] * DIM + coff);
            ACC8(r0)
        }
#undef ACC8
        float inv = 1.0f / fmaxf((float)(end - start), 1.0f);
        union { unsigned short s[8]; uint4 u; } o;
        o.s[0] = f2bf(a0 * inv); o.s[1] = f2bf(a1 * inv);
        o.s[2] = f2bf(a2 * inv); o.s[3] = f2bf(a3 * inv);
        o.s[4] = f2bf(a4 * inv); o.s[5] = f2bf(a5 * inv);
        o.s[6] = f2bf(a6 * inv); o.s[7] = f2bf(a7 * inv);
        *(uint4*)&almp[wave * 4 + q][sub * 8] = o.u;
    }
    __syncthreads();

    // ---- phase 2: MFMA (B-frags loaded per k-step from hot wbuf) ----
    int row = lane & 15;
    int kl  = (lane >> 4) << 3;
    bf16x8 A[8];
    #pragma unroll
    for (int ks = 0; ks < 4; ++ks)
        A[ks] = *(const bf16x8*)&almp[row][kl + ks * 32];
    const unsigned short* xrow = in2b + (size_t)(n0 + row) * DIM + kl;
    #pragma unroll
    for (int ks = 0; ks < 4; ++ks)
        A[4 + ks] = *(const bf16x8*)(xrow + ks * 32);

    const unsigned short* wb0 = wbuf + ((size_t)(wave * 2)     * 8 * 64 + lane) * 8;
    const unsigned short* wb1 = wbuf + ((size_t)(wave * 2 + 1) * 8 * 64 + lane) * 8;
    f32x4 acc0 = {0.f, 0.f, 0.f, 0.f}, acc1 = {0.f, 0.f, 0.f, 0.f};
    #pragma unroll
    for (int ks = 0; ks < 8; ++ks) {
        bf16x8 b0 = *(const bf16x8*)(wb0 + (size_t)ks * 64 * 8);
        bf16x8 b1 = *(const bf16x8*)(wb1 + (size_t)ks * 64 * 8);
        acc0 = __builtin_amdgcn_mfma_f32_16x16x32_bf16(A[ks], b0, acc0, 0, 0, 0);
        acc1 = __builtin_amdgcn_mfma_f32_16x16x32_bf16(A[ks], b1, acc1, 0, 0, 0);
    }

    // C/D layout: col = lane&15, row = (lane>>4)*4 + reg   [m89-verified]
    int o0   = wave * 32;
    int ocol = lane & 15;
    int rb   = (lane >> 4) << 2;
    float b0 = bias[o0 + ocol];
    float b1 = bias[o0 + 16 + ocol];

    if (POOL) {
        float v0[4], v1[4];
        #pragma unroll
        for (int r = 0; r < 4; ++r) {
            v0[r] = fmaxf(acc0[r] + b0, 0.f);
            v1[r] = fmaxf(acc1[r] + b1, 0.f);
        }
        int g0 = sb[0], g15 = sb[15];
        if (g0 == g15) {
            float s0 = v0[0] + v0[1] + v0[2] + v0[3];
            float s1 = v1[0] + v1[1] + v1[2] + v1[3];
            s0 += __shfl_xor(s0, 16); s0 += __shfl_xor(s0, 32);
            s1 += __shfl_xor(s1, 16); s1 += __shfl_xor(s1, 32);
            if (lane < 16) {
                atomicAdd(&gsum[g0 * DIM + o0 + ocol], s0);
                atomicAdd(&gsum[g0 * DIM + o0 + 16 + ocol], s1);
            }
        } else {
            #pragma unroll
            for (int r = 0; r < 4; ++r) {
                int g = sb[rb + r];
                atomicAdd(&gsum[g * DIM + o0 + ocol], v0[r]);
                atomicAdd(&gsum[g * DIM + o0 + 16 + ocol], v1[r]);
            }
        }
    } else {
        #pragma unroll
        for (int r = 0; r < 4; ++r) {
            size_t n = (size_t)(n0 + rb + r);
            outb[n * DIM + o0 + ocol]      = f2bf(fmaxf(acc0[r] + b0, 0.f));
            outb[n * DIM + o0 + 16 + ocol] = f2bf(fmaxf(acc1[r] + b1, 0.f));
        }
    }
}

// ---------------------------------------------------------------------------
// Head: per-graph mean (count via binary search on sorted batch) + MLP +
// sigmoid. One block per graph.
// ---------------------------------------------------------------------------
__global__ __launch_bounds__(256) void k_head(const float* __restrict__ gsum,
                                              const int* __restrict__ batch,
                                              const float* __restrict__ wl1,
                                              const float* __restrict__ bl1,
                                              const float* __restrict__ wout,
                                              const float* __restrict__ bout,
                                              float* __restrict__ out) {
    int g = blockIdx.x;
    int t = threadIdx.x;

    int lo = 0, hi = N_NODES;
    while (lo < hi) { int mid = (lo + hi) >> 1; if (batch[mid] < g) lo = mid + 1; else hi = mid; }
    int s = lo;
    lo = 0; hi = N_NODES;
    while (lo < hi) { int mid = (lo + hi) >> 1; if (batch[mid] < g + 1) lo = mid + 1; else hi = mid; }
    int e = lo;

    __shared__ float gvec[DIM];
    if (t < DIM) {
        float cnt = fmaxf((float)(e - s), 1.0f);
        gvec[t] = gsum[g * DIM + t] / cnt;
    }
    __syncthreads();
    if (t < 64) {
        float a = bl1[t];
        #pragma unroll 4
        for (int k = 0; k < DIM; ++k) a += wl1[t * DIM + k] * gvec[k];
        float g1 = fmaxf(a, 0.f) * wout[t];
        #pragma unroll
        for (int off = 32; off > 0; off >>= 1) g1 += __shfl_down(g1, off);
        if (t == 0) {
            float z = g1 + bout[0];
            out[g] = 1.0f / (1.0f + expf(-z));
        }
    }
}

// ---------------------------------------------------------------------------
extern "C" void kernel_launch(void* const* d_in, const int* in_sizes, int n_in,
                              void* d_out, int out_size, void* d_ws, size_t ws_size,
                              hipStream_t stream) {
    const float* x     = (const float*)d_in[0];
    const int*   ei    = (const int*)d_in[1];    // int64 in ref -> int32 here
    const int*   batch = (const int*)d_in[2];
    const float* w1l   = (const float*)d_in[3];
    const float* b1l   = (const float*)d_in[4];
    const float* w1r   = (const float*)d_in[5];
    const float* w2l   = (const float*)d_in[6];
    const float* b2l   = (const float*)d_in[7];
    const float* w2r   = (const float*)d_in[8];
    const float* wl1   = (const float*)d_in[9];
    const float* bl1   = (const float*)d_in[10];
    const float* wout  = (const float*)d_in[11];
    const float* bout  = (const float*)d_in[12];
    float* out = (float*)d_out;

    char*  wsp = (char*)d_ws;
    size_t off = 0;
    auto alloc = [&](size_t bytes) -> char* {
        char* p = wsp + off;
        off += (bytes + 255) & ~(size_t)255;
        return p;
    };
    int*  bcur = (int*)alloc((size_t)NB * BPAD * 4);
    int2* rsse = (int2*)alloc((size_t)N_NODES * 8);
    int*  srcs = (int*)alloc((size_t)NB * CAP * 4);
    unsigned* tmp = (unsigned*)alloc((size_t)NB * CAP * 4);
    unsigned short* xb    = (unsigned short*)alloc((size_t)N_NODES * DIM * 2);
    unsigned short* h1b   = (unsigned short*)alloc((size_t)N_NODES * DIM * 2);
    unsigned short* wbuf1 = (unsigned short*)alloc((size_t)8 * 8 * 64 * 8 * 2);
    unsigned short* wbuf2 = (unsigned short*)alloc((size_t)8 * 8 * 64 * 8 * 2);
    float* gsum = (float*)alloc((size_t)N_GRAPHS * DIM * 4);

    hipMemsetAsync(bcur, 0, (size_t)NB * BPAD * 4, stream);

    // fused front: edge bucketing || (bf16 convert + weight packs)
    k_front<<<NBB + NPREP, 512, 0, stream>>>(ei, bcur, tmp, x, xb,
                                             w1l, w1r, w2l, w2r, wbuf1, wbuf2);
    // local CSR (+ gsum zeroing)
    k_csr<<<NB, 512, 0, stream>>>(tmp, bcur, rsse, srcs, gsum);

    // conv1 (fused aggregate + GEMM)
    k_sage<0><<<N_NODES / 16, 256, 0, stream>>>(xb, xb, rsse, srcs, wbuf1, b1l,
                                                h1b, batch, gsum);
    // conv2 + fused global_mean_pool stage 1 (no h2 materialization)
    k_sage<1><<<N_NODES / 16, 256, 0, stream>>>(h1b, h1b, rsse, srcs, wbuf2, b2l,
                                                nullptr, batch, gsum);
    // head
    k_head<<<N_GRAPHS, 256, 0, stream>>>(gsum, batch, wl1, bl1, wout, bout, out);
}